// Round 6
// baseline (635.717 us; speedup 1.0000x reference)
//
#include <hip/hip_runtime.h>
#include <hip/hip_bf16.h>
#include <math.h>

// ---------------------------------------------------------------------------
// HydraFusionHead: B=4, IN_CH=256, HEAD_CH=64, H=W=128, NH=4, KEY=VAL=16
// conv_base: 32x32x16 bf16 MFMA implicit GEMM (M=192, N=128/block), writes
//   feats directly into the padded interleaved bf16 buffer (b16) -> pass_b
//   eliminated. conv_head reads b16 feats, writes maps to b16 + fp32 out.
// kv: sparse-tap convs (9/16/25 taps) as bf16 MFMA on b16. attn/q: bf16 MFMA.
// ---------------------------------------------------------------------------

#define HW 16384
#define WIMG 128

typedef unsigned short ushortT;
typedef __attribute__((ext_vector_type(8))) short short8;
typedef __attribute__((ext_vector_type(4))) float floatx4;
typedef __attribute__((ext_vector_type(16))) float floatx16;

// ws layout (float offsets)
constexpr size_t OFF_Q     = 12582912;             // fp32 [4][64][HW]
constexpr size_t OFF_KV    = 16777216;             // bf16 [3][4][128][HW]
constexpr size_t OFF_A16   = 29360128;             // bf16 [4][32][130][130][8]
constexpr size_t OFF_B16   = 38012928;             // bf16 [4][28][134][134][8]
constexpr size_t OFF_CWT   = 46057216;             // bf16 wA32 [9][16][2][192][8]
constexpr size_t OFF_CB    = OFF_CWT + 442368;     // [3][64] fp32
constexpr size_t OFF_HWT   = OFF_CB + 192;         // [3][64][9][12] fp32 zero-padded
constexpr size_t OFF_QWT   = OFF_HWT + 20736;      // bf16 wQ
constexpr size_t OFF_QB    = OFF_QWT + 16384;      // [64]
constexpr size_t OFF_KVW   = OFF_QB + 64;          // bf16 W_eff [472][128][8]
constexpr size_t OFF_GEO   = OFF_KVW + 241664;     // fp32 [3][3][128]
constexpr size_t OFF_P1WT  = OFF_GEO + 1152;       // bf16 wP1
constexpr size_t OFF_P1B   = OFF_P1WT + 81920;     // [256]

struct P53 { const float* p[53]; };

__device__ inline ushortT f2bf(float f) {
    unsigned u = __float_as_uint(f);
    unsigned r = (u + 0x7FFFu + ((u >> 16) & 1u)) >> 16;
    return (ushortT)r;
}
__device__ inline unsigned packbf(float a, float b) {
    return (unsigned)f2bf(a) | ((unsigned)f2bf(b) << 16);
}
__device__ inline float bf2f(ushortT u) {
    return __uint_as_float((unsigned)u << 16);
}

// sample-point offsets (pixel units), faithful to torch .view(2,n) reinterpret
__device__ const float c_ox[3][9] = {
    {-1.f, 0.f, 1.f, -1.f, 0.f, 1.f, -1.f, 0.f, 1.f},
    {-1.f, 2.4375f, -1.f, -2.4375f, 1.f, 2.4375f, 1.f, -2.4375f, 0.f},
    {-1.625f, -1.625f, -1.625f, 0.f, -1.625f, 1.625f, 0.f, -1.625f, 0.f}};
__device__ const float c_oy[3][9] = {
    {-1.f, -1.f, -1.f, 0.f, 0.f, 0.f, 1.f, 1.f, 1.f},
    {2.4375f, -1.f, -2.4375f, -1.f, 2.4375f, 1.f, -2.4375f, 1.f, 0.f},
    {0.f, 0.f, 1.625f, 1.625f, -1.625f, 1.625f, 0.f, 1.625f, 1.625f}};

// corner-branch tap tables (16 taps)
__device__ const int tapX_cor[16] = {-1,-1, 2, 3,-1,-1,-3,-2, 1, 1, 2, 3, 1, 1,-3,-2};
__device__ const int tapY_cor[16] = { 2, 3,-1,-1,-3,-2,-1,-1, 2, 3, 1, 1,-3,-2, 1, 1};
__device__ const int tapR_cor[16] = { 4, 5, 2, 2, 0, 1, 2, 2, 4, 5, 3, 3, 0, 1, 3, 3};

__device__ inline float cornw(float off, int X) {
    float f = floorf(off);
    float d = off - f;
    int fi = (int)f;
    return (X == fi) ? (1.f - d) : (X == fi + 1) ? d : 0.f;
}

// --------------------------- prep: fold BN + transpose ----------------------
__global__ __launch_bounds__(256) void prep_kernel(P53 ptrs, float* __restrict__ ws) {
    int i = blockIdx.x * 256 + threadIdx.x;
    const float* const* p = ptrs.p;
    if (i < 442368) {  // wA32[tap][pairG16][half2][M192][j8], ic = pairG*16+half*8+j
        int j = i & 7; int t = i >> 3;
        int m = t % 192; t /= 192;
        int hf = t & 1; t >>= 1;
        int pairG = t & 15; int tap = t >> 4;
        int br = m >> 6, oc = m & 63, ic = pairG * 16 + hf * 8 + j;
        float v = p[1 + 6 * br][(oc * 256 + ic) * 9 + tap] * p[3 + 6 * br][oc];
        ((ushortT*)(ws + OFF_CWT))[i] = f2bf(v);
        return;
    }
    i -= 442368;
    if (i < 192) {
        int br = i >> 6, oc = i & 63;
        ws[OFF_CB + i] = p[2 + 6 * br][oc] * p[3 + 6 * br][oc] + p[4 + 6 * br][oc];
        return;
    }
    i -= 192;
    if (i < 20736) {  // head conv weights [br][c64][k9][12] zero-padded
        int j = i % 12, k = (i / 12) % 9, c = (i / 108) % 64, br = i / 6912;
        int cnt = (br == 1) ? 12 : 3;
        const float* hw = (br == 0) ? p[5] : (br == 1) ? p[11] : p[17];
        ws[OFF_HWT + i] = (j < cnt) ? hw[(j * 64 + c) * 9 + k] : 0.f;
        return;
    }
    i -= 20736;
    if (i < 16384) {  // bf16 wQ[kk8][sub4][m64][j8]
        int j = i & 7, m = (i >> 3) & 63, sg = i >> 9;
        int k = (sg >> 2) * 32 + (sg & 3) * 8 + j;
        ((ushortT*)(ws + OFF_QWT))[i] = f2bf(p[19][m * 256 + k] * p[21][m]);
        return;
    }
    i -= 16384;
    if (i < 64) { ws[OFF_QB + i] = p[20][i] * p[21][i] + p[22][i]; return; }
    i -= 64;
    if (i < 483328) {  // W_eff bf16: units ctr[0,84) cor0[84,164) cor1[164,244) fg[244,472)
        int j = i & 7, m = (i >> 3) & 127, ug = i >> 10;
        int br, NG, NT, n, C, chb, ul;
        if (ug < 84)       { br = 0; NG = 9; NT = 9;  n = 9; C = 67; chb = 0;  ul = ug; }
        else if (ug < 164) { br = 1; NG = 5; NT = 16; n = 8; C = 76; chb = 0;  ul = ug - 84; }
        else if (ug < 244) { br = 1; NG = 5; NT = 16; n = 8; C = 76; chb = 40; ul = ug - 164; }
        else               { br = 2; NG = 9; NT = 25; n = 9; C = 67; chb = 0;  ul = ug - 244; }
        int t = ul / NG, g = ul % NG;
        int c = chb + g * 8 + j;
        float v = 0.f;
        if (t < NT && c < C) {
            int X, Y;
            if (br == 0)      { X = t % 3 - 1; Y = t / 3 - 1; }
            else if (br == 1) { X = tapX_cor[t]; Y = tapY_cor[t]; }
            else              { X = t % 5 - 2; Y = t / 5 - 2; }
            const float* wsrc = (m < 64) ? p[23 + 8 * br] : p[27 + 8 * br];
            int mo = (m < 64) ? m : m - 64;
            float sc = (m < 64) ? p[25 + 8 * br][mo] : p[29 + 8 * br][mo];
            int Cn = (C + 2) * n;
            float s = 0.f;
            for (int pp = 0; pp < n; ++pp) {
                float ww = cornw(c_ox[br][pp], X) * cornw(c_oy[br][pp], Y);
                if (ww != 0.f) s += ww * wsrc[mo * Cn + c * n + pp];
            }
            v = s * sc;
        }
        ((ushortT*)(ws + OFF_KVW))[i] = f2bf(v);
        return;
    }
    i -= 483328;
    if (i < 1152) {  // geo GA/GB/GC [br][which][128]
        int br = i / 384, rem = i % 384, which = rem >> 7, m = rem & 127;
        int n = (br == 1) ? 8 : 9, C = (br == 1) ? 76 : 67, Cn = (C + 2) * n;
        const float* wsrc = (m < 64) ? p[23 + 8 * br] : p[27 + 8 * br];
        int mo = (m < 64) ? m : m - 64;
        float sc = (m < 64) ? p[25 + 8 * br][mo] : p[29 + 8 * br][mo];
        float bb = (m < 64) ? p[24 + 8 * br][mo] : p[28 + 8 * br][mo];
        float tt = (m < 64) ? p[26 + 8 * br][mo] : p[30 + 8 * br][mo];
        float v = 0.f;
        if (which == 0) {
            for (int pp = 0; pp < n; ++pp) v += wsrc[mo * Cn + C * n + pp];
            v *= sc;
        } else if (which == 1) {
            for (int pp = 0; pp < n; ++pp) v += wsrc[mo * Cn + (C + 1) * n + pp];
            v *= sc;
        } else {
            for (int pp = 0; pp < n; ++pp)
                v += wsrc[mo * Cn + C * n + pp] * c_ox[br][pp]
                   + wsrc[mo * Cn + (C + 1) * n + pp] * c_oy[br][pp];
            v = v * sc * 0.0078125f + bb * sc + tt;
        }
        ws[OFF_GEO + br * 384 + which * 128 + m] = v;
        return;
    }
    i -= 1152;
    if (i < 81920) {  // bf16 wP1[kk10][sub4][M256][j8], K=320 extended
        int j = i & 7, M = (i >> 3) & 255, sg = i >> 11;
        int k = (sg >> 2) * 32 + (sg & 3) * 8 + j;
        int nh = M >> 6, oc = M & 63;
        float sc = p[49][nh * 64 + oc];
        float v;
        if (k < 256) v = p[47][(nh * 64 + oc) * 272 + k] * sc;
        else {
            int k2 = k - 256, nh2 = k2 >> 4, va = k2 & 15;
            v = (nh2 == nh) ? p[47][(nh * 64 + oc) * 272 + 256 + va] * sc : 0.f;
        }
        ((ushortT*)(ws + OFF_P1WT))[i] = f2bf(v);
        return;
    }
    i -= 81920;
    if (i < 256) { ws[OFF_P1B + i] = p[48][i] * p[49][i] + p[50][i]; return; }
}

// ---------- pass A: base fp32 -> padded interleaved bf16 (pad 1) ------------
__global__ __launch_bounds__(256) void pass_a(const float* __restrict__ base,
                                              ushortT* __restrict__ dst) {
    int idx = blockIdx.x * 256 + threadIdx.x;
    if (idx >= 4 * 32 * 130 * 130) return;
    int col = idx % 130, t = idx / 130;
    int row = t % 130; t /= 130;
    int icg = t & 31, b = t >> 5;
    int h = row - 1, w = col - 1;
    unsigned wds[4] = {0u, 0u, 0u, 0u};
    if ((unsigned)h < 128u && (unsigned)w < 128u) {
        const float* s = base + (size_t)(b * 256 + icg * 8) * HW + h * WIMG + w;
        #pragma unroll
        for (int jp = 0; jp < 4; ++jp)
            wds[jp] = packbf(s[(size_t)(2 * jp) * HW], s[(size_t)(2 * jp + 1) * HW]);
    }
    unsigned* d = (unsigned*)(dst + (size_t)idx * 8);
    d[0] = wds[0]; d[1] = wds[1]; d[2] = wds[2]; d[3] = wds[3];
}

// ---------------- zero the 3-px apron of b16 (once per launch) --------------
__global__ __launch_bounds__(256) void border_zero(ushortT* __restrict__ b16) {
    int idx = blockIdx.x * 256 + threadIdx.x;
    if (idx >= 4 * 28 * 134 * 134) return;
    int col = idx % 134, row = (idx / 134) % 134;
    if (row < 3 || row >= 131 || col < 3 || col >= 131) {
        unsigned* d = (unsigned*)(b16 + (size_t)idx * 8);
        d[0] = 0u; d[1] = 0u; d[2] = 0u; d[3] = 0u;
    }
}

// ---- conv3x3 base(256) -> 192 feats via 32x32x16 bf16 MFMA -> b16 ----------
// Block: 4 waves in 2x2 (Mhalf 96 x Nhalf 64); M=192, N=128 (full row).
__global__ __launch_bounds__(256) void conv_base_mfma32(
    const ushortT* __restrict__ a16, const ushortT* __restrict__ wA,
    const float* __restrict__ cb, ushortT* __restrict__ b16)
{
    const int wv = threadIdx.x >> 6, lane = threadIdx.x & 63;
    const int half = lane >> 5, l32 = lane & 31;
    const int mrow = wv >> 1, ncol = wv & 1;
    const int h = blockIdx.x, b = blockIdx.y;
    __shared__ __align__(16) ushortT sbuf[8 * 3 * 130 * 8];  // 49,920 B

    floatx16 acc[3][2];
    #pragma unroll
    for (int mt = 0; mt < 3; ++mt)
        #pragma unroll
        for (int nt = 0; nt < 2; ++nt)
            #pragma unroll
            for (int r = 0; r < 16; ++r) acc[mt][nt][r] = 0.f;

    for (int s = 0; s < 4; ++s) {
        __syncthreads();
        for (int it = 0; it < 13; ++it) {
            int idx = threadIdx.x + it * 256;
            if (idx < 3120) {
                int col = idx % 130, t2 = idx / 130;
                int r = t2 % 3, icg = t2 / 3;
                *(short8*)(sbuf + (size_t)idx * 8) = *(const short8*)(a16 +
                    (((size_t)(b * 32 + s * 8 + icg) * 130 + (h + r)) * 130 + col) * 8);
            }
        }
        __syncthreads();
        #pragma unroll
        for (int tap = 0; tap < 9; ++tap) {
            const int ky = tap / 3, kx = tap % 3;
            #pragma unroll
            for (int pair = 0; pair < 4; ++pair) {
                const int icgl = pair * 2 + half;
                short8 Bf[2];
                #pragma unroll
                for (int nt = 0; nt < 2; ++nt) {
                    int c = ncol * 64 + nt * 32 + l32 + kx;
                    Bf[nt] = *(const short8*)(sbuf + ((icgl * 3 + ky) * 130 + c) * 8);
                }
                short8 Af[3];
                #pragma unroll
                for (int mt = 0; mt < 3; ++mt) {
                    int m = mrow * 96 + mt * 32 + l32;
                    Af[mt] = *(const short8*)(wA +
                        ((((size_t)tap * 16 + (s * 4 + pair)) * 2 + half) * 192 + m) * 8);
                }
                #pragma unroll
                for (int mt = 0; mt < 3; ++mt)
                    #pragma unroll
                    for (int nt = 0; nt < 2; ++nt)
                        acc[mt][nt] = __builtin_amdgcn_mfma_f32_32x32x16_bf16(
                            Af[mt], Bf[nt], acc[mt][nt], 0, 0, 0);
            }
        }
    }
    // epilogue: bias+relu -> b16 (bf16, 4ch packed 8B stores)
    // C/D: col=l32, row = (reg&3) + 8*(reg>>2) + 4*half
    #pragma unroll
    for (int mt = 0; mt < 3; ++mt)
        #pragma unroll
        for (int nt = 0; nt < 2; ++nt) {
            int px = ncol * 64 + nt * 32 + l32;
            #pragma unroll
            for (int q = 0; q < 4; ++q) {
                int ocq = mrow * 96 + mt * 32 + q * 8 + 4 * half;  // 4-aligned
                unsigned lo, hi;
                {
                    float v0 = fmaxf(acc[mt][nt][q * 4 + 0] + cb[ocq + 0], 0.f);
                    float v1 = fmaxf(acc[mt][nt][q * 4 + 1] + cb[ocq + 1], 0.f);
                    float v2 = fmaxf(acc[mt][nt][q * 4 + 2] + cb[ocq + 2], 0.f);
                    float v3 = fmaxf(acc[mt][nt][q * 4 + 3] + cb[ocq + 3], 0.f);
                    lo = packbf(v0, v1); hi = packbf(v2, v3);
                }
                int br = ocq >> 6, oc = ocq & 63;
                int grp = ((br == 0) ? 0 : (br == 1) ? 9 : 19) + (oc >> 3);
                int j0 = oc & 7;  // 0 or 4
                unsigned* d = (unsigned*)(b16 +
                    (((size_t)(b * 28 + grp) * 134 + (h + 3)) * 134 + (px + 3)) * 8 + j0);
                d[0] = lo; d[1] = hi;
            }
        }
}

// ------- head 3x3 convs (64 -> 3/12/3): read b16 feats, write out + b16 -----
__global__ __launch_bounds__(256) void conv_head_kernel(
    ushortT* __restrict__ b16, const float* __restrict__ hwt_all,
    const float* __restrict__ chb, const float* __restrict__ ohb,
    const float* __restrict__ fhb, float* __restrict__ out)
{
    const int tx = threadIdx.x & 15, ty = threadIdx.x >> 4;
    const int w0 = blockIdx.x << 4, h0 = blockIdx.y << 4;
    const int br = blockIdx.z % 3, b = blockIdx.z / 3;
    const int cnt = (br == 1) ? 12 : 3;
    const int mapb = (br == 0) ? 0 : (br == 1) ? 3 : 15;
    const int grpb = (br == 0) ? 0 : (br == 1) ? 9 : 19;
    const float* bias = (br == 0) ? chb : (br == 1) ? ohb : fhb;
    const float* hwt = hwt_all + br * 6912;
    __shared__ float tile[4][18][18];
    float acc[12];
    #pragma unroll
    for (int j = 0; j < 12; ++j) acc[j] = (j < cnt) ? bias[j] : 0.f;
    for (int c0 = 0; c0 < 64; c0 += 4) {
        __syncthreads();
        for (int i = threadIdx.x; i < 1296; i += 256) {
            int cc = i / 324, r = (i % 324) / 18, col = i % 18;
            int c = c0 + cc;
            // borders of b16 are zero -> no bounds check
            tile[cc][r][col] = bf2f(b16[
                ((((size_t)(b * 28 + grpb + (c >> 3)) * 134) + (h0 + r + 2)) * 134
                 + (w0 + col + 2)) * 8 + (c & 7)]);
        }
        __syncthreads();
        #pragma unroll
        for (int cc = 0; cc < 4; ++cc) {
            float in[9];
            #pragma unroll
            for (int ky = 0; ky < 3; ++ky)
                #pragma unroll
                for (int kx = 0; kx < 3; ++kx)
                    in[ky * 3 + kx] = tile[cc][ty + ky][tx + kx];
            const float* wr = hwt + (c0 + cc) * 108;
            #pragma unroll
            for (int k = 0; k < 9; ++k)
                #pragma unroll
                for (int j = 0; j < 12; ++j)
                    acc[j] = fmaf(wr[k * 12 + j], in[k], acc[j]);
        }
    }
    // fp32 output channels
    float* ob = out + ((size_t)b * 26 + mapb) * HW + (h0 + ty) * WIMG + (w0 + tx);
    #pragma unroll
    for (int j = 0; j < 12; ++j)
        if (j < cnt) ob[j * HW] = acc[j];
    // bf16 maps into b16 group(s) 8(,9), zero tail channels
    {
        size_t pxe = ((size_t)(b * 28 + grpb + 8) * 134 + (h0 + ty + 3)) * 134
                     + (w0 + tx + 3);
        unsigned* d = (unsigned*)(b16 + pxe * 8);
        d[0] = packbf(acc[0], acc[1]);
        d[1] = packbf(acc[2], (cnt > 3) ? acc[3] : 0.f);
        d[2] = (cnt > 3) ? packbf(acc[4], acc[5]) : 0u;
        d[3] = (cnt > 3) ? packbf(acc[6], acc[7]) : 0u;
        if (br == 1) {
            unsigned* d2 = (unsigned*)(b16 + (pxe + (size_t)134 * 134) * 8);
            d2[0] = packbf(acc[8], acc[9]);
            d2[1] = packbf(acc[10], acc[11]);
            d2[2] = 0u; d2[3] = 0u;
        }
    }
}

// ----------------------------- q via bf16 MFMA ------------------------------
__global__ __launch_bounds__(256) void q_mfma(float* __restrict__ ws)
{
    const int wv = threadIdx.x >> 6, lane = threadIdx.x & 63;
    const int sub = lane >> 4, ln = lane & 15;
    const int px0 = blockIdx.x * 64, b = blockIdx.y;
    const ushortT* wQ = (const ushortT*)(ws + OFF_QWT);
    const ushortT* a16 = (const ushortT*)(ws + OFF_A16);
    const float* qb = ws + OFF_QB;
    __shared__ __align__(16) ushortT xb[32 * 64 * 8];

    const int mypx = threadIdx.x & 63, q4 = threadIdx.x >> 6;
    const int gpx = px0 + mypx, hh = gpx >> 7, ww = gpx & 127;
    #pragma unroll
    for (int g2 = 0; g2 < 8; ++g2) {
        int g = q4 * 8 + g2;
        short8 v = *(const short8*)(a16 +
            (((size_t)(b * 32 + g) * 130 + (hh + 1)) * 130 + (ww + 1)) * 8);
        *(short8*)(xb + ((size_t)g * 64 + mypx) * 8) = v;
    }
    __syncthreads();

    floatx4 acc[4];
    #pragma unroll
    for (int mt = 0; mt < 4; ++mt)
        #pragma unroll
        for (int r = 0; r < 4; ++r) acc[mt][r] = 0.f;
    #pragma unroll
    for (int kk = 0; kk < 8; ++kk) {
        short8 Bf = *(const short8*)(xb + (((kk * 4 + sub) * 64) + wv * 16 + ln) * 8);
        #pragma unroll
        for (int mt = 0; mt < 4; ++mt) {
            short8 Af = *(const short8*)(wQ + (((kk * 4 + sub) * 64) + mt * 16 + ln) * 8);
            acc[mt] = __builtin_amdgcn_mfma_f32_16x16x32_bf16(Af, Bf, acc[mt], 0, 0, 0);
        }
    }
    float* q = ws + OFF_Q + (size_t)b * 64 * HW;
    #pragma unroll
    for (int mt = 0; mt < 4; ++mt)
        #pragma unroll
        for (int r = 0; r < 4; ++r) {
            int Mi = mt * 16 + sub * 4 + r;
            q[(size_t)Mi * HW + px0 + wv * 16 + ln] = fmaxf(acc[mt][r] + qb[Mi], 0.f);
        }
}

// ------------- kv as sparse-tap conv via bf16 MFMA --------------------------
template<int BR, int NGRP, int NTAP, int ROWS, int COLS, int XMIN, int NCHUNK,
         int NPH, int UBASE>
__global__ __launch_bounds__(256) void kv_conv(
    const ushortT* __restrict__ b16, const ushortT* __restrict__ wU0,
    const float* __restrict__ geo, ushortT* __restrict__ kvout)
{
    const int wv = threadIdx.x >> 6, lane = threadIdx.x & 63;
    const int sub = lane >> 4, ln = lane & 15;
    const int x0 = blockIdx.x * 64, h = blockIdx.y, b = blockIdx.z;
    __shared__ __align__(16) ushortT sbuf[NGRP * ROWS * COLS * 8];

    floatx4 acc[2][4];
    #pragma unroll
    for (int mt = 0; mt < 2; ++mt)
        #pragma unroll
        for (int nt = 0; nt < 4; ++nt)
            #pragma unroll
            for (int r = 0; r < 4; ++r) acc[mt][nt][r] = 0.f;

    #pragma unroll
    for (int ph = 0; ph < NPH; ++ph) {
        const ushortT* wU = wU0 + (size_t)ph * (NCHUNK * 4 * 1024);
        __syncthreads();
        constexpr int NELEM = NGRP * ROWS * COLS;
        for (int it = 0; it < (NELEM + 255) / 256; ++it) {
            int idx = threadIdx.x + it * 256;
            if (idx < NELEM) {
                int col = idx % COLS, t2 = idx / COLS;
                int r = t2 % ROWS, grp = t2 / ROWS;
                int dy = (ROWS == 6) ? ((r < 3) ? r - 3 : r - 2) : (r - ROWS / 2);
                const ushortT* g = b16 +
                    (((size_t)(b * 28 + UBASE + ph * NGRP + grp) * 134 + (h + dy + 3)) * 134
                     + (x0 + col + XMIN + 3)) * 8;
                *(short8*)(sbuf + (size_t)idx * 8) = *(const short8*)g;
            }
        }
        __syncthreads();
        #pragma unroll
        for (int k = 0; k < NCHUNK; ++k) {
            int u = k * 4 + sub;
            int t = u / NGRP, g = u - t * NGRP;
            if (t >= NTAP) t = 0;  // padded units: A weights are zero
            int dxv, ry;
            if (BR == 0)      { dxv = t % 3 - 1; ry = t / 3; }
            else if (BR == 1) { dxv = tapX_cor[t]; ry = tapR_cor[t]; }
            else              { dxv = t % 5 - 2; ry = t / 5; }
            int bbase = (g * ROWS + ry) * COLS + (dxv - XMIN);
            short8 Bf[4];
            #pragma unroll
            for (int nt = 0; nt < 4; ++nt)
                Bf[nt] = *(const short8*)(sbuf + (bbase + nt * 16 + ln) * 8);
            short8 Af[2];
            #pragma unroll
            for (int mt = 0; mt < 2; ++mt)
                Af[mt] = *(const short8*)(wU + ((size_t)u * 128 + wv * 32 + mt * 16 + ln) * 8);
            #pragma unroll
            for (int mt = 0; mt < 2; ++mt)
                #pragma unroll
                for (int nt = 0; nt < 4; ++nt)
                    acc[mt][nt] = __builtin_amdgcn_mfma_f32_16x16x32_bf16(
                        Af[mt], Bf[nt], acc[mt][nt], 0, 0, 0);
        }
    }
    const float fy = (h + 0.5f) * 0.0078125f;
    #pragma unroll
    for (int mt = 0; mt < 2; ++mt)
        #pragma unroll
        for (int nt = 0; nt < 4; ++nt) {
            int px = x0 + nt * 16 + ln;
            float fx = (px + 0.5f) * 0.0078125f;
            #pragma unroll
            for (int r = 0; r < 4; ++r) {
                int Mi = wv * 32 + mt * 16 + sub * 4 + r;
                float v = acc[mt][nt][r] + geo[Mi] * fx + geo[128 + Mi] * fy + geo[256 + Mi];
                kvout[((size_t)(BR * 4 + b) * 128 + Mi) * HW + h * WIMG + px] =
                    f2bf(fmaxf(v, 0.f));
            }
        }
}

// ---------- attention softmax + p1(MFMA, K=320) + relu + p2 -> out ----------
__global__ __launch_bounds__(256) void attn_pred_mfma(
    float* __restrict__ ws, const float* __restrict__ p2w,
    const float* __restrict__ p2b, float* __restrict__ out)
{
    const int wv = threadIdx.x >> 6, lane = threadIdx.x & 63;
    const int sub = lane >> 4, ln = lane & 15;
    const int px0 = blockIdx.x * 64, b = blockIdx.y;
    const ushortT* wP1 = (const ushortT*)(ws + OFF_P1WT);
    const ushortT* a16 = (const ushortT*)(ws + OFF_A16);
    const ushortT* kv = (const ushortT*)(ws + OFF_KV);
    const float* p1b = ws + OFF_P1B;
    __shared__ __align__(16) ushortT xbuf[40 * 64 * 8];

    const int mypx = threadIdx.x & 63, nh = threadIdx.x >> 6;
    const int gpx = px0 + mypx, hh = gpx >> 7, ww = gpx & 127;
    #pragma unroll
    for (int g2 = 0; g2 < 8; ++g2) {
        int g = nh * 8 + g2;
        short8 v = *(const short8*)(a16 +
            (((size_t)(b * 32 + g) * 130 + (hh + 1)) * 130 + (ww + 1)) * 8);
        *(short8*)(xbuf + ((size_t)g * 64 + mypx) * 8) = v;
    }
    {
        const float* q = ws + OFF_Q + ((size_t)b * 64 + nh * 16) * HW + gpx;
        float l[3];
        #pragma unroll
        for (int br = 0; br < 3; ++br) {
            float s = 0.f;
            #pragma unroll
            for (int ko = 0; ko < 16; ++ko)
                s = fmaf(q[(size_t)ko * HW],
                         bf2f(kv[(size_t)((br * 4 + b) * 128 + nh * 16 + ko) * HW + gpx]), s);
            l[br] = s;
        }
        float m = fmaxf(l[0], fmaxf(l[1], l[2]));
        float e0 = __expf(l[0] - m), e1 = __expf(l[1] - m), e2 = __expf(l[2] - m);
        float inv = 1.f / (e0 + e1 + e2);
        float aw0 = e0 * inv, aw1 = e1 * inv, aw2 = e2 * inv;
        #pragma unroll
        for (int vap = 0; vap < 8; ++vap) {
            int va0 = vap * 2, va1 = vap * 2 + 1;
            float a0 =
                aw0 * bf2f(kv[(size_t)((0 * 4 + b) * 128 + 64 + nh * 16 + va0) * HW + gpx]) +
                aw1 * bf2f(kv[(size_t)((1 * 4 + b) * 128 + 64 + nh * 16 + va0) * HW + gpx]) +
                aw2 * bf2f(kv[(size_t)((2 * 4 + b) * 128 + 64 + nh * 16 + va0) * HW + gpx]);
            float a1 =
                aw0 * bf2f(kv[(size_t)((0 * 4 + b) * 128 + 64 + nh * 16 + va1) * HW + gpx]) +
                aw1 * bf2f(kv[(size_t)((1 * 4 + b) * 128 + 64 + nh * 16 + va1) * HW + gpx]) +
                aw2 * bf2f(kv[(size_t)((2 * 4 + b) * 128 + 64 + nh * 16 + va1) * HW + gpx]);
            int g = 32 + nh * 2 + (vap >> 2), wo = vap & 3;
            ((unsigned*)xbuf)[(g * 64 + mypx) * 4 + wo] = packbf(a0, a1);
        }
    }
    __syncthreads();

    floatx4 acc[4][4];
    #pragma unroll
    for (int mt = 0; mt < 4; ++mt)
        #pragma unroll
        for (int nt = 0; nt < 4; ++nt)
            #pragma unroll
            for (int r = 0; r < 4; ++r) acc[mt][nt][r] = 0.f;
    #pragma unroll
    for (int kk = 0; kk < 10; ++kk) {
        short8 Bf[4];
        #pragma unroll
        for (int nt = 0; nt < 4; ++nt)
            Bf[nt] = *(const short8*)(xbuf + (((kk * 4 + sub) * 64) + nt * 16 + ln) * 8);
        #pragma unroll
        for (int mt = 0; mt < 4; ++mt) {
            short8 Af = *(const short8*)(wP1 +
                (((size_t)(kk * 4 + sub) * 256) + wv * 64 + mt * 16 + ln) * 8);
            #pragma unroll
            for (int nt = 0; nt < 4; ++nt)
                acc[mt][nt] = __builtin_amdgcn_mfma_f32_16x16x32_bf16(Af, Bf[nt], acc[mt][nt], 0, 0, 0);
        }
    }

    float po0[4] = {0.f, 0.f, 0.f, 0.f}, po1[4] = {0.f, 0.f, 0.f, 0.f};
    #pragma unroll
    for (int mt = 0; mt < 4; ++mt)
        #pragma unroll
        for (int r = 0; r < 4; ++r) {
            int oc = mt * 16 + sub * 4 + r;
            float bias = p1b[wv * 64 + oc];
            float w0 = p2w[(wv * 2 + 0) * 64 + oc];
            float w1 = p2w[(wv * 2 + 1) * 64 + oc];
            #pragma unroll
            for (int nt = 0; nt < 4; ++nt) {
                float hv = fmaxf(acc[mt][nt][r] + bias, 0.f);
                po0[nt] = fmaf(w0, hv, po0[nt]);
                po1[nt] = fmaf(w1, hv, po1[nt]);
            }
        }
    #pragma unroll
    for (int nt = 0; nt < 4; ++nt) {
        po0[nt] += __shfl_xor(po0[nt], 16);
        po0[nt] += __shfl_xor(po0[nt], 32);
        po1[nt] += __shfl_xor(po1[nt], 16);
        po1[nt] += __shfl_xor(po1[nt], 32);
    }
    if (sub == 0) {
        #pragma unroll
        for (int nt = 0; nt < 4; ++nt) {
            int px = px0 + nt * 16 + ln;
            out[((size_t)b * 26 + 18 + wv * 2 + 0) * HW + px] = po0[nt] + p2b[wv * 2 + 0];
            out[((size_t)b * 26 + 18 + wv * 2 + 1) * HW + px] = po1[nt] + p2b[wv * 2 + 1];
        }
    }
}

// ---------------------------------------------------------------------------
extern "C" void kernel_launch(void* const* d_in, const int* in_sizes, int n_in,
                              void* d_out, int out_size, void* d_ws, size_t ws_size,
                              hipStream_t stream) {
    (void)in_sizes; (void)n_in; (void)out_size; (void)ws_size;
    float* ws  = (float*)d_ws;
    float* out = (float*)d_out;
    const float* base = (const float*)d_in[0];
    P53 ptrs;
    for (int i = 0; i < 53; ++i) ptrs.p[i] = (const float*)d_in[i];

    ushortT* a16 = (ushortT*)(ws + OFF_A16);
    ushortT* b16 = (ushortT*)(ws + OFF_B16);
    ushortT* kvb = (ushortT*)(ws + OFF_KV);

    prep_kernel<<<4088, 256, 0, stream>>>(ptrs, ws);
    pass_a<<<8450, 256, 0, stream>>>(base, a16);
    border_zero<<<7856, 256, 0, stream>>>(b16);
    conv_base_mfma32<<<dim3(128, 4), 256, 0, stream>>>(
        a16, (const ushortT*)(ws + OFF_CWT), ws + OFF_CB, b16);
    conv_head_kernel<<<dim3(8, 8, 12), 256, 0, stream>>>(b16, ws + OFF_HWT,
                                                         (const float*)d_in[6],
                                                         (const float*)d_in[12],
                                                         (const float*)d_in[18], out);
    q_mfma<<<dim3(256, 4), 256, 0, stream>>>(ws);

    const ushortT* kvw = (const ushortT*)(ws + OFF_KVW);
    kv_conv<0, 9, 9, 3, 66, -1, 21, 1, 0><<<dim3(2, 128, 4), 256, 0, stream>>>(
        b16, kvw, ws + OFF_GEO, kvb);
    kv_conv<1, 5, 16, 6, 70, -3, 20, 2, 9><<<dim3(2, 128, 4), 256, 0, stream>>>(
        b16, kvw + 86016, ws + OFF_GEO + 384, kvb);
    kv_conv<2, 9, 25, 5, 68, -2, 57, 1, 19><<<dim3(2, 128, 4), 256, 0, stream>>>(
        b16, kvw + 249856, ws + OFF_GEO + 768, kvb);

    attn_pred_mfma<<<dim3(256, 4), 256, 0, stream>>>(ws, (const float*)d_in[51],
                                                     (const float*)d_in[52], out);
}

// Round 7
// 468.633 us; speedup vs baseline: 1.3565x; 1.3565x over previous
//
#include <hip/hip_runtime.h>
#include <hip/hip_bf16.h>
#include <math.h>

// ---------------------------------------------------------------------------
// HydraFusionHead: B=4, IN_CH=256, HEAD_CH=64, H=W=128, NH=4, KEY=VAL=16
// conv_base: 16x16x32 bf16 MFMA implicit GEMM (M=192, N=64/block, 1024 blocks)
//   writing feats directly into padded interleaved bf16 (b16).
// conv_head: MFMA sparse-tap conv (M=16 padded maps) -> d_out + b16.
// kv: sparse-tap convs (9/16/25 taps) as bf16 MFMA on b16.
// attn+predict: fused q-GEMM + softmax + p1 GEMM (K=320) + p2 epilogue.
// ---------------------------------------------------------------------------

#define HW 16384
#define WIMG 128

typedef unsigned short ushortT;
typedef __attribute__((ext_vector_type(8))) short short8;
typedef __attribute__((ext_vector_type(4))) float floatx4;

// ws layout (float offsets)
constexpr size_t OFF_KV    = 16777216;             // bf16 [3][4][128][HW]
constexpr size_t OFF_A16   = 29360128;             // bf16 [4][32][130][130][8]
constexpr size_t OFF_B16   = 38012928;             // bf16 [4][28][134][134][8]
constexpr size_t OFF_CWT   = 46057216;             // bf16 wA [9][32][192][8]
constexpr size_t OFF_CB    = OFF_CWT + 442368;     // [3][64] fp32
constexpr size_t OFF_HWT   = OFF_CB + 192;         // bf16 wH [3][72][16][8] (27648 us)
constexpr size_t OFF_QWT   = OFF_HWT + 20736;      // bf16 wQ
constexpr size_t OFF_QB    = OFF_QWT + 16384;      // [64]
constexpr size_t OFF_KVW   = OFF_QB + 64;          // bf16 W_eff [472][128][8]
constexpr size_t OFF_GEO   = OFF_KVW + 241664;     // fp32 [3][3][128]
constexpr size_t OFF_P1WT  = OFF_GEO + 1152;       // bf16 wP1
constexpr size_t OFF_P1B   = OFF_P1WT + 81920;     // [256]

struct P53 { const float* p[53]; };

__device__ inline ushortT f2bf(float f) {
    unsigned u = __float_as_uint(f);
    unsigned r = (u + 0x7FFFu + ((u >> 16) & 1u)) >> 16;
    return (ushortT)r;
}
__device__ inline unsigned packbf(float a, float b) {
    return (unsigned)f2bf(a) | ((unsigned)f2bf(b) << 16);
}
__device__ inline float bf2f(ushortT u) {
    return __uint_as_float((unsigned)u << 16);
}

// sample-point offsets (pixel units), faithful to torch .view(2,n) reinterpret
__device__ const float c_ox[3][9] = {
    {-1.f, 0.f, 1.f, -1.f, 0.f, 1.f, -1.f, 0.f, 1.f},
    {-1.f, 2.4375f, -1.f, -2.4375f, 1.f, 2.4375f, 1.f, -2.4375f, 0.f},
    {-1.625f, -1.625f, -1.625f, 0.f, -1.625f, 1.625f, 0.f, -1.625f, 0.f}};
__device__ const float c_oy[3][9] = {
    {-1.f, -1.f, -1.f, 0.f, 0.f, 0.f, 1.f, 1.f, 1.f},
    {2.4375f, -1.f, -2.4375f, -1.f, 2.4375f, 1.f, -2.4375f, 1.f, 0.f},
    {0.f, 0.f, 1.625f, 1.625f, -1.625f, 1.625f, 0.f, 1.625f, 1.625f}};

// corner-branch tap tables (16 taps)
__device__ const int tapX_cor[16] = {-1,-1, 2, 3,-1,-1,-3,-2, 1, 1, 2, 3, 1, 1,-3,-2};
__device__ const int tapY_cor[16] = { 2, 3,-1,-1,-3,-2,-1,-1, 2, 3, 1, 1,-3,-2, 1, 1};
__device__ const int tapR_cor[16] = { 4, 5, 2, 2, 0, 1, 2, 2, 4, 5, 3, 3, 0, 1, 3, 3};

__device__ inline float cornw(float off, int X) {
    float f = floorf(off);
    float d = off - f;
    int fi = (int)f;
    return (X == fi) ? (1.f - d) : (X == fi + 1) ? d : 0.f;
}

// --------------------------- prep: fold BN + transpose ----------------------
__global__ __launch_bounds__(256) void prep_kernel(P53 ptrs, float* __restrict__ ws) {
    int i = blockIdx.x * 256 + threadIdx.x;
    const float* const* p = ptrs.p;
    if (i < 442368) {  // bf16 wA[tap][g32][M192][j8], ic = g*8+j
        int tap = i / 49152, r = i % 49152;
        int g = r / 1536, r2 = r % 1536;
        int M = r2 >> 3, j = r2 & 7;
        int br = M >> 6, oc = M & 63, ic = g * 8 + j;
        float v = p[1 + 6 * br][(oc * 256 + ic) * 9 + tap] * p[3 + 6 * br][oc];
        ((ushortT*)(ws + OFF_CWT))[i] = f2bf(v);
        return;
    }
    i -= 442368;
    if (i < 192) {
        int br = i >> 6, oc = i & 63;
        ws[OFF_CB + i] = p[2 + 6 * br][oc] * p[3 + 6 * br][oc] + p[4 + 6 * br][oc];
        return;
    }
    i -= 192;
    if (i < 27648) {  // bf16 wH[br][u72][m16][j8]: u = t*8+g, ic = g*8+j
        int j = i & 7, m = (i >> 3) & 15, u = (i >> 7) % 72, br = i / 9216;
        int cnt = (br == 1) ? 12 : 3;
        int t = u >> 3, g = u & 7, ic = g * 8 + j;
        const float* hw = (br == 0) ? p[5] : (br == 1) ? p[11] : p[17];
        float v = (m < cnt) ? hw[(m * 64 + ic) * 9 + t] : 0.f;
        ((ushortT*)(ws + OFF_HWT))[i] = f2bf(v);
        return;
    }
    i -= 27648;
    if (i < 16384) {  // bf16 wQ[kk8][sub4][m64][j8]
        int j = i & 7, m = (i >> 3) & 63, sg = i >> 9;
        int k = (sg >> 2) * 32 + (sg & 3) * 8 + j;
        ((ushortT*)(ws + OFF_QWT))[i] = f2bf(p[19][m * 256 + k] * p[21][m]);
        return;
    }
    i -= 16384;
    if (i < 64) { ws[OFF_QB + i] = p[20][i] * p[21][i] + p[22][i]; return; }
    i -= 64;
    if (i < 483328) {  // W_eff bf16: units ctr[0,84) cor0[84,164) cor1[164,244) fg[244,472)
        int j = i & 7, m = (i >> 3) & 127, ug = i >> 10;
        int br, NG, NT, n, C, chb, ul;
        if (ug < 84)       { br = 0; NG = 9; NT = 9;  n = 9; C = 67; chb = 0;  ul = ug; }
        else if (ug < 164) { br = 1; NG = 5; NT = 16; n = 8; C = 76; chb = 0;  ul = ug - 84; }
        else if (ug < 244) { br = 1; NG = 5; NT = 16; n = 8; C = 76; chb = 40; ul = ug - 164; }
        else               { br = 2; NG = 9; NT = 25; n = 9; C = 67; chb = 0;  ul = ug - 244; }
        int t = ul / NG, g = ul % NG;
        int c = chb + g * 8 + j;
        float v = 0.f;
        if (t < NT && c < C) {
            int X, Y;
            if (br == 0)      { X = t % 3 - 1; Y = t / 3 - 1; }
            else if (br == 1) { X = tapX_cor[t]; Y = tapY_cor[t]; }
            else              { X = t % 5 - 2; Y = t / 5 - 2; }
            const float* wsrc = (m < 64) ? p[23 + 8 * br] : p[27 + 8 * br];
            int mo = (m < 64) ? m : m - 64;
            float sc = (m < 64) ? p[25 + 8 * br][mo] : p[29 + 8 * br][mo];
            int Cn = (C + 2) * n;
            float s = 0.f;
            for (int pp = 0; pp < n; ++pp) {
                float ww = cornw(c_ox[br][pp], X) * cornw(c_oy[br][pp], Y);
                if (ww != 0.f) s += ww * wsrc[mo * Cn + c * n + pp];
            }
            v = s * sc;
        }
        ((ushortT*)(ws + OFF_KVW))[i] = f2bf(v);
        return;
    }
    i -= 483328;
    if (i < 1152) {  // geo GA/GB/GC [br][which][128]
        int br = i / 384, rem = i % 384, which = rem >> 7, m = rem & 127;
        int n = (br == 1) ? 8 : 9, C = (br == 1) ? 76 : 67, Cn = (C + 2) * n;
        const float* wsrc = (m < 64) ? p[23 + 8 * br] : p[27 + 8 * br];
        int mo = (m < 64) ? m : m - 64;
        float sc = (m < 64) ? p[25 + 8 * br][mo] : p[29 + 8 * br][mo];
        float bb = (m < 64) ? p[24 + 8 * br][mo] : p[28 + 8 * br][mo];
        float tt = (m < 64) ? p[26 + 8 * br][mo] : p[30 + 8 * br][mo];
        float v = 0.f;
        if (which == 0) {
            for (int pp = 0; pp < n; ++pp) v += wsrc[mo * Cn + C * n + pp];
            v *= sc;
        } else if (which == 1) {
            for (int pp = 0; pp < n; ++pp) v += wsrc[mo * Cn + (C + 1) * n + pp];
            v *= sc;
        } else {
            for (int pp = 0; pp < n; ++pp)
                v += wsrc[mo * Cn + C * n + pp] * c_ox[br][pp]
                   + wsrc[mo * Cn + (C + 1) * n + pp] * c_oy[br][pp];
            v = v * sc * 0.0078125f + bb * sc + tt;
        }
        ws[OFF_GEO + br * 384 + which * 128 + m] = v;
        return;
    }
    i -= 1152;
    if (i < 81920) {  // bf16 wP1[kk10][sub4][M256][j8], K=320 extended
        int j = i & 7, M = (i >> 3) & 255, sg = i >> 11;
        int k = (sg >> 2) * 32 + (sg & 3) * 8 + j;
        int nh = M >> 6, oc = M & 63;
        float sc = p[49][nh * 64 + oc];
        float v;
        if (k < 256) v = p[47][(nh * 64 + oc) * 272 + k] * sc;
        else {
            int k2 = k - 256, nh2 = k2 >> 4, va = k2 & 15;
            v = (nh2 == nh) ? p[47][(nh * 64 + oc) * 272 + 256 + va] * sc : 0.f;
        }
        ((ushortT*)(ws + OFF_P1WT))[i] = f2bf(v);
        return;
    }
    i -= 81920;
    if (i < 256) { ws[OFF_P1B + i] = p[48][i] * p[49][i] + p[50][i]; return; }
}

// ---------- pass A: base fp32 -> padded interleaved bf16 (pad 1) ------------
__global__ __launch_bounds__(256) void pass_a(const float* __restrict__ base,
                                              ushortT* __restrict__ dst) {
    int idx = blockIdx.x * 256 + threadIdx.x;
    if (idx >= 4 * 32 * 130 * 130) return;
    int col = idx % 130, t = idx / 130;
    int row = t % 130; t /= 130;
    int icg = t & 31, b = t >> 5;
    int h = row - 1, w = col - 1;
    unsigned wds[4] = {0u, 0u, 0u, 0u};
    if ((unsigned)h < 128u && (unsigned)w < 128u) {
        const float* s = base + (size_t)(b * 256 + icg * 8) * HW + h * WIMG + w;
        #pragma unroll
        for (int jp = 0; jp < 4; ++jp)
            wds[jp] = packbf(s[(size_t)(2 * jp) * HW], s[(size_t)(2 * jp + 1) * HW]);
    }
    unsigned* d = (unsigned*)(dst + (size_t)idx * 8);
    d[0] = wds[0]; d[1] = wds[1]; d[2] = wds[2]; d[3] = wds[3];
}

// ---------------- zero the 3-px apron of b16 (once per launch) --------------
__global__ __launch_bounds__(256) void border_zero(ushortT* __restrict__ b16) {
    int idx = blockIdx.x * 256 + threadIdx.x;
    if (idx >= 4 * 28 * 134 * 134) return;
    int col = idx % 134, row = (idx / 134) % 134;
    if (row < 3 || row >= 131 || col < 3 || col >= 131) {
        unsigned* d = (unsigned*)(b16 + (size_t)idx * 8);
        d[0] = 0u; d[1] = 0u; d[2] = 0u; d[3] = 0u;
    }
}

// ---- conv3x3 base(256) -> 192 feats via 16x16x32 bf16 MFMA -> b16 ----------
__global__ __launch_bounds__(256) void conv_base_mfma(
    const ushortT* __restrict__ a16, const ushortT* __restrict__ wA,
    const float* __restrict__ cb, ushortT* __restrict__ b16)
{
    const int wv = threadIdx.x >> 6, lane = threadIdx.x & 63;
    const int sub = lane >> 4, ln = lane & 15;
    const int xh = blockIdx.x, h = blockIdx.y, b = blockIdx.z;
    const int x0 = xh * 64;
    __shared__ __align__(16) ushortT sbuf[8 * 3 * 66 * 8];  // 25,344 B

    floatx4 acc[3][4];
    #pragma unroll
    for (int mt = 0; mt < 3; ++mt)
        #pragma unroll
        for (int nt = 0; nt < 4; ++nt)
            #pragma unroll
            for (int r = 0; r < 4; ++r) acc[mt][nt][r] = 0.f;

    for (int s = 0; s < 4; ++s) {
        __syncthreads();
        for (int it = 0; it < 7; ++it) {
            int idx = threadIdx.x + it * 256;
            if (idx < 1584) {
                int col = idx % 66, t2 = idx / 66;
                int r = t2 % 3, icg = t2 / 3;
                *(short8*)(sbuf + (size_t)idx * 8) = *(const short8*)(a16 +
                    (((size_t)(b * 32 + s * 8 + icg) * 130 + (h + r)) * 130 + (x0 + col)) * 8);
            }
        }
        __syncthreads();
        #pragma unroll
        for (int tap = 0; tap < 9; ++tap) {
            const int ky = tap / 3, kx = tap % 3;
            #pragma unroll
            for (int icc = 0; icc < 2; ++icc) {
                const int icgl = icc * 4 + sub;
                short8 Bf[4];
                #pragma unroll
                for (int nt = 0; nt < 4; ++nt) {
                    int c = nt * 16 + ln + kx;
                    Bf[nt] = *(const short8*)(sbuf + ((icgl * 3 + ky) * 66 + c) * 8);
                }
                const int g = s * 8 + icc * 4 + sub;
                short8 Af[3];
                #pragma unroll
                for (int mt = 0; mt < 3; ++mt) {
                    int m = wv * 48 + mt * 16 + ln;
                    Af[mt] = *(const short8*)(wA + (((size_t)tap * 32 + g) * 192 + m) * 8);
                }
                #pragma unroll
                for (int mt = 0; mt < 3; ++mt)
                    #pragma unroll
                    for (int nt = 0; nt < 4; ++nt)
                        acc[mt][nt] = __builtin_amdgcn_mfma_f32_16x16x32_bf16(
                            Af[mt], Bf[nt], acc[mt][nt], 0, 0, 0);
            }
        }
    }
    // epilogue: bias+relu -> b16 (4 consecutive oc per thread, 8-B store)
    #pragma unroll
    for (int mt = 0; mt < 3; ++mt)
        #pragma unroll
        for (int nt = 0; nt < 4; ++nt) {
            int px = x0 + nt * 16 + ln;
            int ocq = wv * 48 + mt * 16 + sub * 4;  // 4-aligned
            float v0 = fmaxf(acc[mt][nt][0] + cb[ocq + 0], 0.f);
            float v1 = fmaxf(acc[mt][nt][1] + cb[ocq + 1], 0.f);
            float v2 = fmaxf(acc[mt][nt][2] + cb[ocq + 2], 0.f);
            float v3 = fmaxf(acc[mt][nt][3] + cb[ocq + 3], 0.f);
            int br = ocq >> 6, oc = ocq & 63;
            int grp = ((br == 0) ? 0 : (br == 1) ? 9 : 19) + (oc >> 3);
            int j0 = oc & 7;  // 0 or 4
            unsigned* d = (unsigned*)(b16 +
                (((size_t)(b * 28 + grp) * 134 + (h + 3)) * 134 + (px + 3)) * 8 + j0);
            d[0] = packbf(v0, v1); d[1] = packbf(v2, v3);
        }
}

// ---- head 3x3 convs via MFMA (M=16 padded maps, K=576) -> out + b16 --------
__global__ __launch_bounds__(256) void conv_head_mfma(
    const ushortT* __restrict__ b16c, const ushortT* __restrict__ wH,
    const float* __restrict__ chb, const float* __restrict__ ohb,
    const float* __restrict__ fhb, float* __restrict__ out,
    ushortT* __restrict__ b16)
{
    const int wv = threadIdx.x >> 6, lane = threadIdx.x & 63;
    const int sub = lane >> 4, ln = lane & 15;
    const int h = blockIdx.x;
    const int br = blockIdx.y % 3, b = blockIdx.y / 3;
    const int cnt = (br == 1) ? 12 : 3;
    const int mapb = (br == 0) ? 0 : (br == 1) ? 3 : 15;
    const int grpb = (br == 0) ? 0 : (br == 1) ? 9 : 19;
    const float* bias = (br == 0) ? chb : (br == 1) ? ohb : fhb;
    __shared__ __align__(16) ushortT sbuf[8 * 3 * 130 * 8];  // 49,920 B

    for (int it = 0; it < 13; ++it) {
        int idx = threadIdx.x + it * 256;
        if (idx < 3120) {
            int col = idx % 130, t2 = idx / 130;
            int r = t2 % 3, g = t2 / 3;
            *(short8*)(sbuf + (size_t)idx * 8) = *(const short8*)(b16c +
                (((size_t)(b * 28 + grpb + g) * 134 + (h + r + 2)) * 134 + (col + 2)) * 8);
        }
    }
    __syncthreads();

    floatx4 acc[2];
    #pragma unroll
    for (int nt = 0; nt < 2; ++nt)
        #pragma unroll
        for (int r = 0; r < 4; ++r) acc[nt][r] = 0.f;
    #pragma unroll
    for (int k = 0; k < 18; ++k) {
        int u = k * 4 + sub;
        int t = u >> 3, g = u & 7;
        int dxv = t % 3 - 1, ry = t / 3;
        short8 Af = *(const short8*)(wH + ((size_t)(br * 72 + u) * 16 + ln) * 8);
        #pragma unroll
        for (int nt = 0; nt < 2; ++nt) {
            int c = wv * 32 + nt * 16 + ln + dxv + 1;
            short8 Bf = *(const short8*)(sbuf + ((g * 3 + ry) * 130 + c) * 8);
            acc[nt] = __builtin_amdgcn_mfma_f32_16x16x32_bf16(Af, Bf, acc[nt], 0, 0, 0);
        }
    }
    #pragma unroll
    for (int nt = 0; nt < 2; ++nt) {
        int px = wv * 32 + nt * 16 + ln;
        #pragma unroll
        for (int r = 0; r < 4; ++r) {
            int m = sub * 4 + r;
            if (m < cnt) {
                float v = acc[nt][r] + bias[m];
                out[((size_t)b * 26 + mapb + m) * HW + h * WIMG + px] = v;
                int grp = grpb + 8 + (m >> 3), j = m & 7;
                b16[(((size_t)(b * 28 + grp) * 134 + (h + 3)) * 134 + (px + 3)) * 8 + j]
                    = f2bf(v);
            }
        }
    }
}

// ------------- kv as sparse-tap conv via bf16 MFMA --------------------------
template<int BR, int NGRP, int NTAP, int ROWS, int COLS, int XMIN, int NCHUNK,
         int NPH, int UBASE>
__global__ __launch_bounds__(256) void kv_conv(
    const ushortT* __restrict__ b16, const ushortT* __restrict__ wU0,
    const float* __restrict__ geo, ushortT* __restrict__ kvout)
{
    const int wv = threadIdx.x >> 6, lane = threadIdx.x & 63;
    const int sub = lane >> 4, ln = lane & 15;
    const int x0 = blockIdx.x * 64, h = blockIdx.y, b = blockIdx.z;
    __shared__ __align__(16) ushortT sbuf[NGRP * ROWS * COLS * 8];

    floatx4 acc[2][4];
    #pragma unroll
    for (int mt = 0; mt < 2; ++mt)
        #pragma unroll
        for (int nt = 0; nt < 4; ++nt)
            #pragma unroll
            for (int r = 0; r < 4; ++r) acc[mt][nt][r] = 0.f;

    #pragma unroll
    for (int ph = 0; ph < NPH; ++ph) {
        const ushortT* wU = wU0 + (size_t)ph * (NCHUNK * 4 * 1024);
        __syncthreads();
        constexpr int NELEM = NGRP * ROWS * COLS;
        for (int it = 0; it < (NELEM + 255) / 256; ++it) {
            int idx = threadIdx.x + it * 256;
            if (idx < NELEM) {
                int col = idx % COLS, t2 = idx / COLS;
                int r = t2 % ROWS, grp = t2 / ROWS;
                int dy = (ROWS == 6) ? ((r < 3) ? r - 3 : r - 2) : (r - ROWS / 2);
                const ushortT* g = b16 +
                    (((size_t)(b * 28 + UBASE + ph * NGRP + grp) * 134 + (h + dy + 3)) * 134
                     + (x0 + col + XMIN + 3)) * 8;
                *(short8*)(sbuf + (size_t)idx * 8) = *(const short8*)g;
            }
        }
        __syncthreads();
        #pragma unroll
        for (int k = 0; k < NCHUNK; ++k) {
            int u = k * 4 + sub;
            int t = u / NGRP, g = u - t * NGRP;
            if (t >= NTAP) t = 0;  // padded units: A weights are zero
            int dxv, ry;
            if (BR == 0)      { dxv = t % 3 - 1; ry = t / 3; }
            else if (BR == 1) { dxv = tapX_cor[t]; ry = tapR_cor[t]; }
            else              { dxv = t % 5 - 2; ry = t / 5; }
            int bbase = (g * ROWS + ry) * COLS + (dxv - XMIN);
            short8 Bf[4];
            #pragma unroll
            for (int nt = 0; nt < 4; ++nt)
                Bf[nt] = *(const short8*)(sbuf + (bbase + nt * 16 + ln) * 8);
            short8 Af[2];
            #pragma unroll
            for (int mt = 0; mt < 2; ++mt)
                Af[mt] = *(const short8*)(wU + ((size_t)u * 128 + wv * 32 + mt * 16 + ln) * 8);
            #pragma unroll
            for (int mt = 0; mt < 2; ++mt)
                #pragma unroll
                for (int nt = 0; nt < 4; ++nt)
                    acc[mt][nt] = __builtin_amdgcn_mfma_f32_16x16x32_bf16(
                        Af[mt], Bf[nt], acc[mt][nt], 0, 0, 0);
        }
    }
    const float fy = (h + 0.5f) * 0.0078125f;
    #pragma unroll
    for (int mt = 0; mt < 2; ++mt)
        #pragma unroll
        for (int nt = 0; nt < 4; ++nt) {
            int px = x0 + nt * 16 + ln;
            float fx = (px + 0.5f) * 0.0078125f;
            #pragma unroll
            for (int r = 0; r < 4; ++r) {
                int Mi = wv * 32 + mt * 16 + sub * 4 + r;
                float v = acc[mt][nt][r] + geo[Mi] * fx + geo[128 + Mi] * fy + geo[256 + Mi];
                kvout[((size_t)(BR * 4 + b) * 128 + Mi) * HW + h * WIMG + px] =
                    f2bf(fmaxf(v, 0.f));
            }
        }
}

// -------- fused q-GEMM + attention softmax + p1(MFMA,K=320) + p2 ------------
__global__ __launch_bounds__(256) void attn_pred_mfma(
    float* __restrict__ ws, const float* __restrict__ p2w,
    const float* __restrict__ p2b, float* __restrict__ out)
{
    const int wv = threadIdx.x >> 6, lane = threadIdx.x & 63;
    const int sub = lane >> 4, ln = lane & 15;
    const int px0 = blockIdx.x * 64, b = blockIdx.y;
    const ushortT* wP1 = (const ushortT*)(ws + OFF_P1WT);
    const ushortT* wQ  = (const ushortT*)(ws + OFF_QWT);
    const ushortT* a16 = (const ushortT*)(ws + OFF_A16);
    const ushortT* kv = (const ushortT*)(ws + OFF_KV);
    const float* p1b = ws + OFF_P1B;
    const float* qb  = ws + OFF_QB;
    __shared__ __align__(16) ushortT xbuf[40 * 64 * 8];  // 40,960 B
    __shared__ __align__(16) ushortT qld[64 * 64];       //  8,192 B

    const int mypx = threadIdx.x & 63, nh = threadIdx.x >> 6;
    const int gpx = px0 + mypx, hh = gpx >> 7, ww = gpx & 127;
    #pragma unroll
    for (int g2 = 0; g2 < 8; ++g2) {
        int g = nh * 8 + g2;
        short8 v = *(const short8*)(a16 +
            (((size_t)(b * 32 + g) * 130 + (hh + 1)) * 130 + (ww + 1)) * 8);
        *(short8*)(xbuf + ((size_t)g * 64 + mypx) * 8) = v;
    }
    __syncthreads();

    // q GEMM: wave wv computes head wv's 16 q-rows over 64 px
    {
        floatx4 qacc[4];
        #pragma unroll
        for (int nt = 0; nt < 4; ++nt)
            #pragma unroll
            for (int r = 0; r < 4; ++r) qacc[nt][r] = 0.f;
        #pragma unroll
        for (int kk = 0; kk < 8; ++kk) {
            short8 Af = *(const short8*)(wQ + (((kk * 4 + sub) * 64) + wv * 16 + ln) * 8);
            #pragma unroll
            for (int nt = 0; nt < 4; ++nt) {
                short8 Bf = *(const short8*)(xbuf + (((kk * 4 + sub) * 64) + nt * 16 + ln) * 8);
                qacc[nt] = __builtin_amdgcn_mfma_f32_16x16x32_bf16(Af, Bf, qacc[nt], 0, 0, 0);
            }
        }
        #pragma unroll
        for (int nt = 0; nt < 4; ++nt)
            #pragma unroll
            for (int r = 0; r < 4; ++r) {
                int row = wv * 16 + sub * 4 + r;
                qld[row * 64 + nt * 16 + ln] = f2bf(fmaxf(qacc[nt][r] + qb[row], 0.f));
            }
    }
    __syncthreads();

    // softmax per (px, head) -> att values into xbuf groups 32..39
    {
        float l[3];
        #pragma unroll
        for (int br = 0; br < 3; ++br) {
            float s = 0.f;
            #pragma unroll
            for (int ko = 0; ko < 16; ++ko)
                s = fmaf(bf2f(qld[(nh * 16 + ko) * 64 + mypx]),
                         bf2f(kv[(size_t)((br * 4 + b) * 128 + nh * 16 + ko) * HW + gpx]), s);
            l[br] = s;
        }
        float m = fmaxf(l[0], fmaxf(l[1], l[2]));
        float e0 = __expf(l[0] - m), e1 = __expf(l[1] - m), e2 = __expf(l[2] - m);
        float inv = 1.f / (e0 + e1 + e2);
        float aw0 = e0 * inv, aw1 = e1 * inv, aw2 = e2 * inv;
        #pragma unroll
        for (int vap = 0; vap < 8; ++vap) {
            int va0 = vap * 2, va1 = vap * 2 + 1;
            float a0 =
                aw0 * bf2f(kv[(size_t)((0 * 4 + b) * 128 + 64 + nh * 16 + va0) * HW + gpx]) +
                aw1 * bf2f(kv[(size_t)((1 * 4 + b) * 128 + 64 + nh * 16 + va0) * HW + gpx]) +
                aw2 * bf2f(kv[(size_t)((2 * 4 + b) * 128 + 64 + nh * 16 + va0) * HW + gpx]);
            float a1 =
                aw0 * bf2f(kv[(size_t)((0 * 4 + b) * 128 + 64 + nh * 16 + va1) * HW + gpx]) +
                aw1 * bf2f(kv[(size_t)((1 * 4 + b) * 128 + 64 + nh * 16 + va1) * HW + gpx]) +
                aw2 * bf2f(kv[(size_t)((2 * 4 + b) * 128 + 64 + nh * 16 + va1) * HW + gpx]);
            int g = 32 + nh * 2 + (vap >> 2), wo = vap & 3;
            ((unsigned*)xbuf)[(g * 64 + mypx) * 4 + wo] = packbf(a0, a1);
        }
    }
    __syncthreads();

    // p1 GEMM: M=256 (wave = head), N=64, K=320
    floatx4 acc[4][4];
    #pragma unroll
    for (int mt = 0; mt < 4; ++mt)
        #pragma unroll
        for (int nt = 0; nt < 4; ++nt)
            #pragma unroll
            for (int r = 0; r < 4; ++r) acc[mt][nt][r] = 0.f;
    #pragma unroll
    for (int kk = 0; kk < 10; ++kk) {
        short8 Bf[4];
        #pragma unroll
        for (int nt = 0; nt < 4; ++nt)
            Bf[nt] = *(const short8*)(xbuf + (((kk * 4 + sub) * 64) + nt * 16 + ln) * 8);
        #pragma unroll
        for (int mt = 0; mt < 4; ++mt) {
            short8 Af = *(const short8*)(wP1 +
                (((size_t)(kk * 4 + sub) * 256) + wv * 64 + mt * 16 + ln) * 8);
            #pragma unroll
            for (int nt = 0; nt < 4; ++nt)
                acc[mt][nt] = __builtin_amdgcn_mfma_f32_16x16x32_bf16(Af, Bf[nt], acc[mt][nt], 0, 0, 0);
        }
    }

    float po0[4] = {0.f, 0.f, 0.f, 0.f}, po1[4] = {0.f, 0.f, 0.f, 0.f};
    #pragma unroll
    for (int mt = 0; mt < 4; ++mt)
        #pragma unroll
        for (int r = 0; r < 4; ++r) {
            int oc = mt * 16 + sub * 4 + r;
            float bias = p1b[wv * 64 + oc];
            float w0 = p2w[(wv * 2 + 0) * 64 + oc];
            float w1 = p2w[(wv * 2 + 1) * 64 + oc];
            #pragma unroll
            for (int nt = 0; nt < 4; ++nt) {
                float hv = fmaxf(acc[mt][nt][r] + bias, 0.f);
                po0[nt] = fmaf(w0, hv, po0[nt]);
                po1[nt] = fmaf(w1, hv, po1[nt]);
            }
        }
    #pragma unroll
    for (int nt = 0; nt < 4; ++nt) {
        po0[nt] += __shfl_xor(po0[nt], 16);
        po0[nt] += __shfl_xor(po0[nt], 32);
        po1[nt] += __shfl_xor(po1[nt], 16);
        po1[nt] += __shfl_xor(po1[nt], 32);
    }
    if (sub == 0) {
        #pragma unroll
        for (int nt = 0; nt < 4; ++nt) {
            int px = px0 + nt * 16 + ln;
            out[((size_t)b * 26 + 18 + wv * 2 + 0) * HW + px] = po0[nt] + p2b[wv * 2 + 0];
            out[((size_t)b * 26 + 18 + wv * 2 + 1) * HW + px] = po1[nt] + p2b[wv * 2 + 1];
        }
    }
}

// ---------------------------------------------------------------------------
extern "C" void kernel_launch(void* const* d_in, const int* in_sizes, int n_in,
                              void* d_out, int out_size, void* d_ws, size_t ws_size,
                              hipStream_t stream) {
    (void)in_sizes; (void)n_in; (void)out_size; (void)ws_size;
    float* ws  = (float*)d_ws;
    float* out = (float*)d_out;
    const float* base = (const float*)d_in[0];
    P53 ptrs;
    for (int i = 0; i < 53; ++i) ptrs.p[i] = (const float*)d_in[i];

    ushortT* a16 = (ushortT*)(ws + OFF_A16);
    ushortT* b16 = (ushortT*)(ws + OFF_B16);
    ushortT* kvb = (ushortT*)(ws + OFF_KV);

    prep_kernel<<<4115, 256, 0, stream>>>(ptrs, ws);
    pass_a<<<8450, 256, 0, stream>>>(base, a16);
    border_zero<<<7856, 256, 0, stream>>>(b16);
    conv_base_mfma<<<dim3(2, 128, 4), 256, 0, stream>>>(
        a16, (const ushortT*)(ws + OFF_CWT), ws + OFF_CB, b16);
    conv_head_mfma<<<dim3(128, 12), 256, 0, stream>>>(
        b16, (const ushortT*)(ws + OFF_HWT),
        (const float*)d_in[6], (const float*)d_in[12], (const float*)d_in[18],
        out, b16);

    const ushortT* kvw = (const ushortT*)(ws + OFF_KVW);
    kv_conv<0, 9, 9, 3, 66, -1, 21, 1, 0><<<dim3(2, 128, 4), 256, 0, stream>>>(
        b16, kvw, ws + OFF_GEO, kvb);
    kv_conv<1, 5, 16, 6, 70, -3, 20, 2, 9><<<dim3(2, 128, 4), 256, 0, stream>>>(
        b16, kvw + 86016, ws + OFF_GEO + 384, kvb);
    kv_conv<2, 9, 25, 5, 68, -2, 57, 1, 19><<<dim3(2, 128, 4), 256, 0, stream>>>(
        b16, kvw + 249856, ws + OFF_GEO + 768, kvb);

    attn_pred_mfma<<<dim3(256, 4), 256, 0, stream>>>(ws, (const float*)d_in[51],
                                                     (const float*)d_in[52], out);
}

// Round 8
// 446.688 us; speedup vs baseline: 1.4232x; 1.0491x over previous
//
#include <hip/hip_runtime.h>
#include <hip/hip_bf16.h>
#include <math.h>

// ---------------------------------------------------------------------------
// HydraFusionHead: B=4, IN_CH=256, HEAD_CH=64, H=W=128, NH=4, KEY=VAL=16
// conv_base: 16x16x32 bf16 MFMA implicit GEMM with register-prefetch
//   pipelined staging, writing straight into padded interleaved bf16 (b16).
// conv_head: MFMA sparse-tap conv -> d_out + b16.
// kv: ONE merged kernel (br runtime), wave tiling M64xN32 (B-frag reuse x4),
//   2-deep fragment pipelining, LDS tap-LUT.
// attn+predict: fused q-GEMM + softmax + p1 GEMM (K=320) + p2 epilogue.
// ---------------------------------------------------------------------------

#define HW 16384
#define WIMG 128

typedef unsigned short ushortT;
typedef __attribute__((ext_vector_type(8))) short short8;
typedef __attribute__((ext_vector_type(4))) float floatx4;

// ws layout (float offsets)
constexpr size_t OFF_KV    = 16777216;             // bf16 [3][4][128][HW]
constexpr size_t OFF_A16   = 29360128;             // bf16 [4][32][130][130][8]
constexpr size_t OFF_B16   = 38012928;             // bf16 [4][28][134][134][8]
constexpr size_t OFF_CWT   = 46057216;             // bf16 wA [9][32][192][8]
constexpr size_t OFF_CB    = OFF_CWT + 442368;     // [3][64] fp32
constexpr size_t OFF_HWT   = OFF_CB + 192;         // bf16 wH [3][72][16][8]
constexpr size_t OFF_QWT   = OFF_HWT + 20736;      // bf16 wQ
constexpr size_t OFF_QB    = OFF_QWT + 16384;      // [64]
constexpr size_t OFF_KVW   = OFF_QB + 64;          // bf16 W_eff [472][128][8]
constexpr size_t OFF_GEO   = OFF_KVW + 241664;     // fp32 [3][3][128]
constexpr size_t OFF_P1WT  = OFF_GEO + 1152;       // bf16 wP1
constexpr size_t OFF_P1B   = OFF_P1WT + 81920;     // [256]

struct P53 { const float* p[53]; };

__device__ inline ushortT f2bf(float f) {
    unsigned u = __float_as_uint(f);
    unsigned r = (u + 0x7FFFu + ((u >> 16) & 1u)) >> 16;
    return (ushortT)r;
}
__device__ inline unsigned packbf(float a, float b) {
    return (unsigned)f2bf(a) | ((unsigned)f2bf(b) << 16);
}
__device__ inline float bf2f(ushortT u) {
    return __uint_as_float((unsigned)u << 16);
}

// sample-point offsets (pixel units), faithful to torch .view(2,n) reinterpret
__device__ const float c_ox[3][9] = {
    {-1.f, 0.f, 1.f, -1.f, 0.f, 1.f, -1.f, 0.f, 1.f},
    {-1.f, 2.4375f, -1.f, -2.4375f, 1.f, 2.4375f, 1.f, -2.4375f, 0.f},
    {-1.625f, -1.625f, -1.625f, 0.f, -1.625f, 1.625f, 0.f, -1.625f, 0.f}};
__device__ const float c_oy[3][9] = {
    {-1.f, -1.f, -1.f, 0.f, 0.f, 0.f, 1.f, 1.f, 1.f},
    {2.4375f, -1.f, -2.4375f, -1.f, 2.4375f, 1.f, -2.4375f, 1.f, 0.f},
    {0.f, 0.f, 1.625f, 1.625f, -1.625f, 1.625f, 0.f, 1.625f, 1.625f}};

// corner-branch tap tables (16 taps)
__device__ const int tapX_cor[16] = {-1,-1, 2, 3,-1,-1,-3,-2, 1, 1, 2, 3, 1, 1,-3,-2};
__device__ const int tapY_cor[16] = { 2, 3,-1,-1,-3,-2,-1,-1, 2, 3, 1, 1,-3,-2, 1, 1};
__device__ const int tapR_cor[16] = { 4, 5, 2, 2, 0, 1, 2, 2, 4, 5, 3, 3, 0, 1, 3, 3};

__device__ inline float cornw(float off, int X) {
    float f = floorf(off);
    float d = off - f;
    int fi = (int)f;
    return (X == fi) ? (1.f - d) : (X == fi + 1) ? d : 0.f;
}

// --------------------------- prep: fold BN + transpose ----------------------
__global__ __launch_bounds__(256) void prep_kernel(P53 ptrs, float* __restrict__ ws) {
    int i = blockIdx.x * 256 + threadIdx.x;
    const float* const* p = ptrs.p;
    if (i < 442368) {  // bf16 wA[tap][g32][M192][j8], ic = g*8+j
        int tap = i / 49152, r = i % 49152;
        int g = r / 1536, r2 = r % 1536;
        int M = r2 >> 3, j = r2 & 7;
        int br = M >> 6, oc = M & 63, ic = g * 8 + j;
        float v = p[1 + 6 * br][(oc * 256 + ic) * 9 + tap] * p[3 + 6 * br][oc];
        ((ushortT*)(ws + OFF_CWT))[i] = f2bf(v);
        return;
    }
    i -= 442368;
    if (i < 192) {
        int br = i >> 6, oc = i & 63;
        ws[OFF_CB + i] = p[2 + 6 * br][oc] * p[3 + 6 * br][oc] + p[4 + 6 * br][oc];
        return;
    }
    i -= 192;
    if (i < 27648) {  // bf16 wH[br][u72][m16][j8]: u = t*8+g, ic = g*8+j
        int j = i & 7, m = (i >> 3) & 15, u = (i >> 7) % 72, br = i / 9216;
        int cnt = (br == 1) ? 12 : 3;
        int t = u >> 3, g = u & 7, ic = g * 8 + j;
        const float* hw = (br == 0) ? p[5] : (br == 1) ? p[11] : p[17];
        float v = (m < cnt) ? hw[(m * 64 + ic) * 9 + t] : 0.f;
        ((ushortT*)(ws + OFF_HWT))[i] = f2bf(v);
        return;
    }
    i -= 27648;
    if (i < 16384) {  // bf16 wQ[kk8][sub4][m64][j8]
        int j = i & 7, m = (i >> 3) & 63, sg = i >> 9;
        int k = (sg >> 2) * 32 + (sg & 3) * 8 + j;
        ((ushortT*)(ws + OFF_QWT))[i] = f2bf(p[19][m * 256 + k] * p[21][m]);
        return;
    }
    i -= 16384;
    if (i < 64) { ws[OFF_QB + i] = p[20][i] * p[21][i] + p[22][i]; return; }
    i -= 64;
    if (i < 483328) {  // W_eff bf16: units ctr[0,84) cor0[84,164) cor1[164,244) fg[244,472)
        int j = i & 7, m = (i >> 3) & 127, ug = i >> 10;
        int br, NG, NT, n, C, chb, ul;
        if (ug < 84)       { br = 0; NG = 9; NT = 9;  n = 9; C = 67; chb = 0;  ul = ug; }
        else if (ug < 164) { br = 1; NG = 5; NT = 16; n = 8; C = 76; chb = 0;  ul = ug - 84; }
        else if (ug < 244) { br = 1; NG = 5; NT = 16; n = 8; C = 76; chb = 40; ul = ug - 164; }
        else               { br = 2; NG = 9; NT = 25; n = 9; C = 67; chb = 0;  ul = ug - 244; }
        int t = ul / NG, g = ul % NG;
        int c = chb + g * 8 + j;
        float v = 0.f;
        if (t < NT && c < C) {
            int X, Y;
            if (br == 0)      { X = t % 3 - 1; Y = t / 3 - 1; }
            else if (br == 1) { X = tapX_cor[t]; Y = tapY_cor[t]; }
            else              { X = t % 5 - 2; Y = t / 5 - 2; }
            const float* wsrc = (m < 64) ? p[23 + 8 * br] : p[27 + 8 * br];
            int mo = (m < 64) ? m : m - 64;
            float sc = (m < 64) ? p[25 + 8 * br][mo] : p[29 + 8 * br][mo];
            int Cn = (C + 2) * n;
            float s = 0.f;
            for (int pp = 0; pp < n; ++pp) {
                float ww = cornw(c_ox[br][pp], X) * cornw(c_oy[br][pp], Y);
                if (ww != 0.f) s += ww * wsrc[mo * Cn + c * n + pp];
            }
            v = s * sc;
        }
        ((ushortT*)(ws + OFF_KVW))[i] = f2bf(v);
        return;
    }
    i -= 483328;
    if (i < 1152) {  // geo GA/GB/GC [br][which][128]
        int br = i / 384, rem = i % 384, which = rem >> 7, m = rem & 127;
        int n = (br == 1) ? 8 : 9, C = (br == 1) ? 76 : 67, Cn = (C + 2) * n;
        const float* wsrc = (m < 64) ? p[23 + 8 * br] : p[27 + 8 * br];
        int mo = (m < 64) ? m : m - 64;
        float sc = (m < 64) ? p[25 + 8 * br][mo] : p[29 + 8 * br][mo];
        float bb = (m < 64) ? p[24 + 8 * br][mo] : p[28 + 8 * br][mo];
        float tt = (m < 64) ? p[26 + 8 * br][mo] : p[30 + 8 * br][mo];
        float v = 0.f;
        if (which == 0) {
            for (int pp = 0; pp < n; ++pp) v += wsrc[mo * Cn + C * n + pp];
            v *= sc;
        } else if (which == 1) {
            for (int pp = 0; pp < n; ++pp) v += wsrc[mo * Cn + (C + 1) * n + pp];
            v *= sc;
        } else {
            for (int pp = 0; pp < n; ++pp)
                v += wsrc[mo * Cn + C * n + pp] * c_ox[br][pp]
                   + wsrc[mo * Cn + (C + 1) * n + pp] * c_oy[br][pp];
            v = v * sc * 0.0078125f + bb * sc + tt;
        }
        ws[OFF_GEO + br * 384 + which * 128 + m] = v;
        return;
    }
    i -= 1152;
    if (i < 81920) {  // bf16 wP1[kk10][sub4][M256][j8], K=320 extended
        int j = i & 7, M = (i >> 3) & 255, sg = i >> 11;
        int k = (sg >> 2) * 32 + (sg & 3) * 8 + j;
        int nh = M >> 6, oc = M & 63;
        float sc = p[49][nh * 64 + oc];
        float v;
        if (k < 256) v = p[47][(nh * 64 + oc) * 272 + k] * sc;
        else {
            int k2 = k - 256, nh2 = k2 >> 4, va = k2 & 15;
            v = (nh2 == nh) ? p[47][(nh * 64 + oc) * 272 + 256 + va] * sc : 0.f;
        }
        ((ushortT*)(ws + OFF_P1WT))[i] = f2bf(v);
        return;
    }
    i -= 81920;
    if (i < 256) { ws[OFF_P1B + i] = p[48][i] * p[49][i] + p[50][i]; return; }
}

// -- pass A+B borders: base -> padded bf16 (pad 1); zero b16 3-px apron ------
__global__ __launch_bounds__(256) void pass_ab(const float* __restrict__ base,
                                               ushortT* __restrict__ a16,
                                               ushortT* __restrict__ b16) {
    int idx = blockIdx.x * 256 + threadIdx.x;
    if (idx < 4 * 32 * 130 * 130) {
        int col = idx % 130, t = idx / 130;
        int row = t % 130; t /= 130;
        int icg = t & 31, b = t >> 5;
        int h = row - 1, w = col - 1;
        unsigned wds[4] = {0u, 0u, 0u, 0u};
        if ((unsigned)h < 128u && (unsigned)w < 128u) {
            const float* s = base + (size_t)(b * 256 + icg * 8) * HW + h * WIMG + w;
            #pragma unroll
            for (int jp = 0; jp < 4; ++jp)
                wds[jp] = packbf(s[(size_t)(2 * jp) * HW], s[(size_t)(2 * jp + 1) * HW]);
        }
        unsigned* d = (unsigned*)(a16 + (size_t)idx * 8);
        d[0] = wds[0]; d[1] = wds[1]; d[2] = wds[2]; d[3] = wds[3];
        return;
    }
    idx -= 4 * 32 * 130 * 130;
    if (idx < 4 * 28 * 134 * 134) {
        int col = idx % 134, row = (idx / 134) % 134;
        if (row < 3 || row >= 131 || col < 3 || col >= 131) {
            unsigned* d = (unsigned*)(b16 + (size_t)idx * 8);
            d[0] = 0u; d[1] = 0u; d[2] = 0u; d[3] = 0u;
        }
    }
}

// ---- conv3x3 base(256) -> 192 feats via 16x16x32 bf16 MFMA -> b16 ----------
// register-prefetch pipelined staging: stage s+1 loads issue during compute(s)
__global__ __launch_bounds__(256) void conv_base_mfma(
    const ushortT* __restrict__ a16, const ushortT* __restrict__ wA,
    const float* __restrict__ cb, ushortT* __restrict__ b16)
{
    const int wv = threadIdx.x >> 6, lane = threadIdx.x & 63;
    const int sub = lane >> 4, ln = lane & 15;
    const int xh = blockIdx.x, h = blockIdx.y, b = blockIdx.z;
    const int x0 = xh * 64;
    __shared__ __align__(16) ushortT sbuf[8 * 3 * 66 * 8];  // 25,344 B

    floatx4 acc[3][4];
    #pragma unroll
    for (int mt = 0; mt < 3; ++mt)
        #pragma unroll
        for (int nt = 0; nt < 4; ++nt)
            #pragma unroll
            for (int r = 0; r < 4; ++r) acc[mt][nt][r] = 0.f;

    short8 pf[7];
    auto do_loads = [&](int s) {
        #pragma unroll
        for (int it = 0; it < 7; ++it) {
            int idx = threadIdx.x + it * 256;
            if (idx < 1584) {
                int col = idx % 66, t2 = idx / 66;
                int r = t2 % 3, icg = t2 / 3;
                pf[it] = *(const short8*)(a16 +
                    (((size_t)(b * 32 + s * 8 + icg) * 130 + (h + r)) * 130 + (x0 + col)) * 8);
            }
        }
    };
    do_loads(0);
    #pragma unroll
    for (int s = 0; s < 4; ++s) {
        __syncthreads();
        #pragma unroll
        for (int it = 0; it < 7; ++it) {
            int idx = threadIdx.x + it * 256;
            if (idx < 1584) *(short8*)(sbuf + (size_t)idx * 8) = pf[it];
        }
        __syncthreads();
        if (s < 3) do_loads(s + 1);
        #pragma unroll
        for (int tap = 0; tap < 9; ++tap) {
            const int ky = tap / 3, kx = tap % 3;
            #pragma unroll
            for (int icc = 0; icc < 2; ++icc) {
                const int icgl = icc * 4 + sub;
                short8 Bf[4];
                #pragma unroll
                for (int nt = 0; nt < 4; ++nt) {
                    int c = nt * 16 + ln + kx;
                    Bf[nt] = *(const short8*)(sbuf + ((icgl * 3 + ky) * 66 + c) * 8);
                }
                const int g = s * 8 + icc * 4 + sub;
                short8 Af[3];
                #pragma unroll
                for (int mt = 0; mt < 3; ++mt) {
                    int m = wv * 48 + mt * 16 + ln;
                    Af[mt] = *(const short8*)(wA + (((size_t)tap * 32 + g) * 192 + m) * 8);
                }
                #pragma unroll
                for (int mt = 0; mt < 3; ++mt)
                    #pragma unroll
                    for (int nt = 0; nt < 4; ++nt)
                        acc[mt][nt] = __builtin_amdgcn_mfma_f32_16x16x32_bf16(
                            Af[mt], Bf[nt], acc[mt][nt], 0, 0, 0);
            }
        }
    }
    // epilogue: bias+relu -> b16 (4 consecutive oc per thread, 8-B store)
    #pragma unroll
    for (int mt = 0; mt < 3; ++mt)
        #pragma unroll
        for (int nt = 0; nt < 4; ++nt) {
            int px = x0 + nt * 16 + ln;
            int ocq = wv * 48 + mt * 16 + sub * 4;
            float v0 = fmaxf(acc[mt][nt][0] + cb[ocq + 0], 0.f);
            float v1 = fmaxf(acc[mt][nt][1] + cb[ocq + 1], 0.f);
            float v2 = fmaxf(acc[mt][nt][2] + cb[ocq + 2], 0.f);
            float v3 = fmaxf(acc[mt][nt][3] + cb[ocq + 3], 0.f);
            int br = ocq >> 6, oc = ocq & 63;
            int grp = ((br == 0) ? 0 : (br == 1) ? 9 : 19) + (oc >> 3);
            int j0 = oc & 7;
            unsigned* d = (unsigned*)(b16 +
                (((size_t)(b * 28 + grp) * 134 + (h + 3)) * 134 + (px + 3)) * 8 + j0);
            d[0] = packbf(v0, v1); d[1] = packbf(v2, v3);
        }
}

// ---- head 3x3 convs via MFMA (M=16 padded maps, K=576) -> out + b16 --------
__global__ __launch_bounds__(256) void conv_head_mfma(
    const ushortT* __restrict__ b16c, const ushortT* __restrict__ wH,
    const float* __restrict__ chb, const float* __restrict__ ohb,
    const float* __restrict__ fhb, float* __restrict__ out,
    ushortT* __restrict__ b16)
{
    const int wv = threadIdx.x >> 6, lane = threadIdx.x & 63;
    const int sub = lane >> 4, ln = lane & 15;
    const int h = blockIdx.x;
    const int br = blockIdx.y % 3, b = blockIdx.y / 3;
    const int cnt = (br == 1) ? 12 : 3;
    const int mapb = (br == 0) ? 0 : (br == 1) ? 3 : 15;
    const int grpb = (br == 0) ? 0 : (br == 1) ? 9 : 19;
    const float* bias = (br == 0) ? chb : (br == 1) ? ohb : fhb;
    __shared__ __align__(16) ushortT sbuf[8 * 3 * 130 * 8];

    for (int it = 0; it < 13; ++it) {
        int idx = threadIdx.x + it * 256;
        if (idx < 3120) {
            int col = idx % 130, t2 = idx / 130;
            int r = t2 % 3, g = t2 / 3;
            *(short8*)(sbuf + (size_t)idx * 8) = *(const short8*)(b16c +
                (((size_t)(b * 28 + grpb + g) * 134 + (h + r + 2)) * 134 + (col + 2)) * 8);
        }
    }
    __syncthreads();

    floatx4 acc[2];
    #pragma unroll
    for (int nt = 0; nt < 2; ++nt)
        #pragma unroll
        for (int r = 0; r < 4; ++r) acc[nt][r] = 0.f;
    #pragma unroll
    for (int k = 0; k < 18; ++k) {
        int u = k * 4 + sub;
        int t = u >> 3, g = u & 7;
        int dxv = t % 3 - 1, ry = t / 3;
        short8 Af = *(const short8*)(wH + ((size_t)(br * 72 + u) * 16 + ln) * 8);
        #pragma unroll
        for (int nt = 0; nt < 2; ++nt) {
            int c = wv * 32 + nt * 16 + ln + dxv + 1;
            short8 Bf = *(const short8*)(sbuf + ((g * 3 + ry) * 130 + c) * 8);
            acc[nt] = __builtin_amdgcn_mfma_f32_16x16x32_bf16(Af, Bf, acc[nt], 0, 0, 0);
        }
    }
    #pragma unroll
    for (int nt = 0; nt < 2; ++nt) {
        int px = wv * 32 + nt * 16 + ln;
        #pragma unroll
        for (int r = 0; r < 4; ++r) {
            int m = sub * 4 + r;
            if (m < cnt) {
                float v = acc[nt][r] + bias[m];
                out[((size_t)b * 26 + mapb + m) * HW + h * WIMG + px] = v;
                int grp = grpb + 8 + (m >> 3), j = m & 7;
                b16[(((size_t)(b * 28 + grp) * 134 + (h + 3)) * 134 + (px + 3)) * 8 + j]
                    = f2bf(v);
            }
        }
    }
}

// ------ merged kv: sparse-tap conv, wave tiling M64xN32, 2-deep pipeline ----
__global__ __launch_bounds__(256) void kv_all(
    const ushortT* __restrict__ b16, const ushortT* __restrict__ kvw,
    const float* __restrict__ geob, ushortT* __restrict__ kvout)
{
    const int lane = threadIdx.x & 63, wv = threadIdx.x >> 6;
    const int sub = lane >> 4, ln = lane & 15;
    const int mw = wv >> 1, nw = wv & 1;
    const int x0 = blockIdx.x * 64, h = blockIdx.y;
    const int brv = blockIdx.z >> 2, b = blockIdx.z & 3;

    const int NGRP = (brv == 1) ? 5 : 9;
    const int NTAP = (brv == 0) ? 9 : (brv == 1) ? 16 : 25;
    const int ROWS = (brv == 0) ? 3 : (brv == 1) ? 6 : 5;
    const int COLS = (brv == 0) ? 66 : (brv == 1) ? 70 : 68;
    const int XMIN = (brv == 0) ? -1 : (brv == 1) ? -3 : -2;
    const int NCHUNK = (brv == 0) ? 21 : (brv == 1) ? 20 : 57;
    const int NPH = (brv == 1) ? 2 : 1;
    const int UBASE = (brv == 0) ? 0 : (brv == 1) ? 9 : 19;
    const ushortT* wU0 = kvw + ((brv == 0) ? 0 : (brv == 1) ? 86016 : 249856);
    const float* geo = geob + brv * 384;

    __shared__ __align__(16) ushortT sbuf[3060 * 8];  // 48,960 B (fg max)
    __shared__ int lut[232];

    // tap LUT: bbase per unit u
    if (threadIdx.x < 4 * NCHUNK) {
        int u = threadIdx.x;
        unsigned Mng = 0xFFFFFFFFu / (unsigned)NGRP + 1u;
        int t = (int)__umulhi((unsigned)u, Mng);
        int g = u - t * NGRP;
        if (t >= NTAP) t = 0;
        int dxv, ry;
        if (brv == 0)      { dxv = t % 3 - 1; ry = t / 3; }
        else if (brv == 1) { dxv = tapX_cor[t]; ry = tapR_cor[t]; }
        else               { dxv = t % 5 - 2; ry = t / 5; }
        lut[u] = (g * ROWS + ry) * COLS + (dxv - XMIN);
    }

    floatx4 acc[4][2];
    #pragma unroll
    for (int mt = 0; mt < 4; ++mt)
        #pragma unroll
        for (int nt = 0; nt < 2; ++nt)
            #pragma unroll
            for (int r = 0; r < 4; ++r) acc[mt][nt][r] = 0.f;

    const unsigned Mcols = 0xFFFFFFFFu / (unsigned)COLS + 1u;
    const unsigned Mrows = 0xFFFFFFFFu / (unsigned)ROWS + 1u;
    const int NELEM = NGRP * ROWS * COLS;

    for (int ph = 0; ph < NPH; ++ph) {
        const ushortT* wU = wU0 + (size_t)ph * (NCHUNK * 4 * 1024);
        __syncthreads();
        for (int idx = threadIdx.x; idx < NELEM; idx += 256) {
            int row = (int)__umulhi((unsigned)idx, Mcols);
            int col = idx - row * COLS;
            int grp = (int)__umulhi((unsigned)row, Mrows);
            int rw = row - grp * ROWS;
            int dy = (ROWS == 6) ? ((rw < 3) ? rw - 3 : rw - 2) : (rw - (ROWS >> 1));
            *(short8*)(sbuf + (size_t)idx * 8) = *(const short8*)(b16 +
                (((size_t)(b * 28 + UBASE + ph * NGRP + grp) * 134 + (h + dy + 3)) * 134
                 + (x0 + col + XMIN + 3)) * 8);
        }
        __syncthreads();

        short8 A0[4], B0[2], A1[4], B1[2];
        auto ldf = [&](int k, short8 A[4], short8 B[2]) {
            int u = k * 4 + sub;
            int bb = lut[u];
            const ushortT* wp = wU + (size_t)u * 1024;
            #pragma unroll
            for (int mt = 0; mt < 4; ++mt)
                A[mt] = *(const short8*)(wp + (mw * 64 + mt * 16 + ln) * 8);
            #pragma unroll
            for (int nt = 0; nt < 2; ++nt)
                B[nt] = *(const short8*)(sbuf + (size_t)(bb + nw * 32 + nt * 16 + ln) * 8);
        };
        auto dom = [&](short8 A[4], short8 B[2]) {
            #pragma unroll
            for (int mt = 0; mt < 4; ++mt)
                #pragma unroll
                for (int nt = 0; nt < 2; ++nt)
                    acc[mt][nt] = __builtin_amdgcn_mfma_f32_16x16x32_bf16(
                        A[mt], B[nt], acc[mt][nt], 0, 0, 0);
        };
        ldf(0, A0, B0);
        for (int k = 0; k < NCHUNK; k += 2) {
            bool h1 = (k + 1 < NCHUNK);
            if (h1) ldf(k + 1, A1, B1);
            dom(A0, B0);
            if (k + 2 < NCHUNK) ldf(k + 2, A0, B0);
            if (h1) dom(A1, B1);
        }
    }

    // epilogue: + GA*fx + GB*fy + GC, relu, bf16 store
    const float fy = (h + 0.5f) * 0.0078125f;
    #pragma unroll
    for (int mt = 0; mt < 4; ++mt)
        #pragma unroll
        for (int nt = 0; nt < 2; ++nt) {
            int px = x0 + nw * 32 + nt * 16 + ln;
            float fx = (px + 0.5f) * 0.0078125f;
            #pragma unroll
            for (int r = 0; r < 4; ++r) {
                int Mi = mw * 64 + mt * 16 + sub * 4 + r;
                float v = acc[mt][nt][r] + geo[Mi] * fx + geo[128 + Mi] * fy + geo[256 + Mi];
                kvout[((size_t)(brv * 4 + b) * 128 + Mi) * HW + h * WIMG + px] =
                    f2bf(fmaxf(v, 0.f));
            }
        }
}

// -------- fused q-GEMM + attention softmax + p1(MFMA,K=320) + p2 ------------
__global__ __launch_bounds__(256) void attn_pred_mfma(
    float* __restrict__ ws, const float* __restrict__ p2w,
    const float* __restrict__ p2b, float* __restrict__ out)
{
    const int wv = threadIdx.x >> 6, lane = threadIdx.x & 63;
    const int sub = lane >> 4, ln = lane & 15;
    const int px0 = blockIdx.x * 64, b = blockIdx.y;
    const ushortT* wP1 = (const ushortT*)(ws + OFF_P1WT);
    const ushortT* wQ  = (const ushortT*)(ws + OFF_QWT);
    const ushortT* a16 = (const ushortT*)(ws + OFF_A16);
    const ushortT* kv = (const ushortT*)(ws + OFF_KV);
    const float* p1b = ws + OFF_P1B;
    const float* qb  = ws + OFF_QB;
    __shared__ __align__(16) ushortT xbuf[40 * 64 * 8];
    __shared__ __align__(16) ushortT qld[64 * 64];

    const int mypx = threadIdx.x & 63, nh = threadIdx.x >> 6;
    const int gpx = px0 + mypx, hh = gpx >> 7, ww = gpx & 127;
    #pragma unroll
    for (int g2 = 0; g2 < 8; ++g2) {
        int g = nh * 8 + g2;
        short8 v = *(const short8*)(a16 +
            (((size_t)(b * 32 + g) * 130 + (hh + 1)) * 130 + (ww + 1)) * 8);
        *(short8*)(xbuf + ((size_t)g * 64 + mypx) * 8) = v;
    }
    __syncthreads();

    {
        floatx4 qacc[4];
        #pragma unroll
        for (int nt = 0; nt < 4; ++nt)
            #pragma unroll
            for (int r = 0; r < 4; ++r) qacc[nt][r] = 0.f;
        #pragma unroll
        for (int kk = 0; kk < 8; ++kk) {
            short8 Af = *(const short8*)(wQ + (((kk * 4 + sub) * 64) + wv * 16 + ln) * 8);
            #pragma unroll
            for (int nt = 0; nt < 4; ++nt) {
                short8 Bf = *(const short8*)(xbuf + (((kk * 4 + sub) * 64) + nt * 16 + ln) * 8);
                qacc[nt] = __builtin_amdgcn_mfma_f32_16x16x32_bf16(Af, Bf, qacc[nt], 0, 0, 0);
            }
        }
        #pragma unroll
        for (int nt = 0; nt < 4; ++nt)
            #pragma unroll
            for (int r = 0; r < 4; ++r) {
                int row = wv * 16 + sub * 4 + r;
                qld[row * 64 + nt * 16 + ln] = f2bf(fmaxf(qacc[nt][r] + qb[row], 0.f));
            }
    }
    __syncthreads();

    {
        float l[3];
        #pragma unroll
        for (int br = 0; br < 3; ++br) {
            float s = 0.f;
            #pragma unroll
            for (int ko = 0; ko < 16; ++ko)
                s = fmaf(bf2f(qld[(nh * 16 + ko) * 64 + mypx]),
                         bf2f(kv[(size_t)((br * 4 + b) * 128 + nh * 16 + ko) * HW + gpx]), s);
            l[br] = s;
        }
        float m = fmaxf(l[0], fmaxf(l[1], l[2]));
        float e0 = __expf(l[0] - m), e1 = __expf(l[1] - m), e2 = __expf(l[2] - m);
        float inv = 1.f / (e0 + e1 + e2);
        float aw0 = e0 * inv, aw1 = e1 * inv, aw2 = e2 * inv;
        #pragma unroll
        for (int vap = 0; vap < 8; ++vap) {
            int va0 = vap * 2, va1 = vap * 2 + 1;
            float a0 =
                aw0 * bf2f(kv[(size_t)((0 * 4 + b) * 128 + 64 + nh * 16 + va0) * HW + gpx]) +
                aw1 * bf2f(kv[(size_t)((1 * 4 + b) * 128 + 64 + nh * 16 + va0) * HW + gpx]) +
                aw2 * bf2f(kv[(size_t)((2 * 4 + b) * 128 + 64 + nh * 16 + va0) * HW + gpx]);
            float a1 =
                aw0 * bf2f(kv[(size_t)((0 * 4 + b) * 128 + 64 + nh * 16 + va1) * HW + gpx]) +
                aw1 * bf2f(kv[(size_t)((1 * 4 + b) * 128 + 64 + nh * 16 + va1) * HW + gpx]) +
                aw2 * bf2f(kv[(size_t)((2 * 4 + b) * 128 + 64 + nh * 16 + va1) * HW + gpx]);
            int g = 32 + nh * 2 + (vap >> 2), wo = vap & 3;
            ((unsigned*)xbuf)[(g * 64 + mypx) * 4 + wo] = packbf(a0, a1);
        }
    }
    __syncthreads();

    floatx4 acc[4][4];
    #pragma unroll
    for (int mt = 0; mt < 4; ++mt)
        #pragma unroll
        for (int nt = 0; nt < 4; ++nt)
            #pragma unroll
            for (int r = 0; r < 4; ++r) acc[mt][nt][r] = 0.f;
    #pragma unroll
    for (int kk = 0; kk < 10; ++kk) {
        short8 Bf[4];
        #pragma unroll
        for (int nt = 0; nt < 4; ++nt)
            Bf[nt] = *(const short8*)(xbuf + (((kk * 4 + sub) * 64) + nt * 16 + ln) * 8);
        #pragma unroll
        for (int mt = 0; mt < 4; ++mt) {
            short8 Af = *(const short8*)(wP1 +
                (((size_t)(kk * 4 + sub) * 256) + wv * 64 + mt * 16 + ln) * 8);
            #pragma unroll
            for (int nt = 0; nt < 4; ++nt)
                acc[mt][nt] = __builtin_amdgcn_mfma_f32_16x16x32_bf16(Af, Bf[nt], acc[mt][nt], 0, 0, 0);
        }
    }

    float po0[4] = {0.f, 0.f, 0.f, 0.f}, po1[4] = {0.f, 0.f, 0.f, 0.f};
    #pragma unroll
    for (int mt = 0; mt < 4; ++mt)
        #pragma unroll
        for (int r = 0; r < 4; ++r) {
            int oc = mt * 16 + sub * 4 + r;
            float bias = p1b[wv * 64 + oc];
            float w0 = p2w[(wv * 2 + 0) * 64 + oc];
            float w1 = p2w[(wv * 2 + 1) * 64 + oc];
            #pragma unroll
            for (int nt = 0; nt < 4; ++nt) {
                float hv = fmaxf(acc[mt][nt][r] + bias, 0.f);
                po0[nt] = fmaf(w0, hv, po0[nt]);
                po1[nt] = fmaf(w1, hv, po1[nt]);
            }
        }
    #pragma unroll
    for (int nt = 0; nt < 4; ++nt) {
        po0[nt] += __shfl_xor(po0[nt], 16);
        po0[nt] += __shfl_xor(po0[nt], 32);
        po1[nt] += __shfl_xor(po1[nt], 16);
        po1[nt] += __shfl_xor(po1[nt], 32);
    }
    if (sub == 0) {
        #pragma unroll
        for (int nt = 0; nt < 4; ++nt) {
            int px = px0 + nt * 16 + ln;
            out[((size_t)b * 26 + 18 + wv * 2 + 0) * HW + px] = po0[nt] + p2b[wv * 2 + 0];
            out[((size_t)b * 26 + 18 + wv * 2 + 1) * HW + px] = po1[nt] + p2b[wv * 2 + 1];
        }
    }
}

// ---------------------------------------------------------------------------
extern "C" void kernel_launch(void* const* d_in, const int* in_sizes, int n_in,
                              void* d_out, int out_size, void* d_ws, size_t ws_size,
                              hipStream_t stream) {
    (void)in_sizes; (void)n_in; (void)out_size; (void)ws_size;
    float* ws  = (float*)d_ws;
    float* out = (float*)d_out;
    const float* base = (const float*)d_in[0];
    P53 ptrs;
    for (int i = 0; i < 53; ++i) ptrs.p[i] = (const float*)d_in[i];

    ushortT* a16 = (ushortT*)(ws + OFF_A16);
    ushortT* b16 = (ushortT*)(ws + OFF_B16);
    ushortT* kvb = (ushortT*)(ws + OFF_KV);

    prep_kernel<<<4115, 256, 0, stream>>>(ptrs, ws);
    pass_ab<<<16306, 256, 0, stream>>>(base, a16, b16);
    conv_base_mfma<<<dim3(2, 128, 4), 256, 0, stream>>>(
        a16, (const ushortT*)(ws + OFF_CWT), ws + OFF_CB, b16);
    conv_head_mfma<<<dim3(128, 12), 256, 0, stream>>>(
        b16, (const ushortT*)(ws + OFF_HWT),
        (const float*)d_in[6], (const float*)d_in[12], (const float*)d_in[18],
        out, b16);
    kv_all<<<dim3(2, 128, 12), 256, 0, stream>>>(
        b16, (const ushortT*)(ws + OFF_KVW), ws + OFF_GEO, kvb);
    attn_pred_mfma<<<dim3(256, 4), 256, 0, stream>>>(ws, (const float*)d_in[51],
                                                     (const float*)d_in[52], out);
}

// Round 9
// 435.353 us; speedup vs baseline: 1.4602x; 1.0260x over previous
//
#include <hip/hip_runtime.h>
#include <hip/hip_bf16.h>
#include <math.h>

// ---------------------------------------------------------------------------
// HydraFusionHead: B=4, IN_CH=256, HEAD_CH=64, H=W=128, NH=4, KEY=VAL=16
// conv_base: 16x16x32 bf16 MFMA implicit GEMM, 8 half-stages with
//   double-buffered LDS + global_load_lds async staging; epilogue shfl-
//   combined full-16B stores into padded interleaved bf16 (b16).
// conv_head: MFMA sparse-tap conv (async staging) -> d_out + b16.
// kv: ONE merged kernel, wave tiling M64xN32, async staging, LDS tap-LUT.
// attn+predict: fused q-GEMM + softmax + p1 GEMM (K=320) + p2 epilogue.
// ---------------------------------------------------------------------------

#define HW 16384
#define WIMG 128

typedef unsigned short ushortT;
typedef __attribute__((ext_vector_type(8))) short short8;
typedef __attribute__((ext_vector_type(4))) float floatx4;
typedef __attribute__((ext_vector_type(4))) unsigned uintx4;

// ws layout (float offsets)
constexpr size_t OFF_KV    = 16777216;             // bf16 [3][4][128][HW]
constexpr size_t OFF_A16   = 29360128;             // bf16 [4][32][130][130][8]
constexpr size_t OFF_B16   = 38012928;             // bf16 [4][28][134][134][8]
constexpr size_t OFF_CWT   = 46057216;             // bf16 wA [9][32][192][8]
constexpr size_t OFF_CB    = OFF_CWT + 442368;     // [3][64] fp32
constexpr size_t OFF_HWT   = OFF_CB + 192;         // bf16 wH [3][72][16][8]
constexpr size_t OFF_QWT   = OFF_HWT + 20736;      // bf16 wQ
constexpr size_t OFF_QB    = OFF_QWT + 16384;      // [64]
constexpr size_t OFF_KVW   = OFF_QB + 64;          // bf16 W_eff [472][128][8]
constexpr size_t OFF_GEO   = OFF_KVW + 241664;     // fp32 [3][3][128]
constexpr size_t OFF_P1WT  = OFF_GEO + 1152;       // bf16 wP1
constexpr size_t OFF_P1B   = OFF_P1WT + 81920;     // [256]

struct P53 { const float* p[53]; };

__device__ inline ushortT f2bf(float f) {
    unsigned u = __float_as_uint(f);
    unsigned r = (u + 0x7FFFu + ((u >> 16) & 1u)) >> 16;
    return (ushortT)r;
}
__device__ inline unsigned packbf(float a, float b) {
    return (unsigned)f2bf(a) | ((unsigned)f2bf(b) << 16);
}
__device__ inline float bf2f(ushortT u) {
    return __uint_as_float((unsigned)u << 16);
}

// async global->LDS 16B: lds dst = wave-uniform base + lane*16
typedef __attribute__((address_space(3))) ushortT lds_us;
typedef __attribute__((address_space(1))) const ushortT glb_us;
__device__ inline void gload_lds16(const ushortT* g, ushortT* ldsbase) {
    __builtin_amdgcn_global_load_lds((glb_us*)g, (lds_us*)ldsbase, 16, 0, 0);
}

// sample-point offsets (pixel units), faithful to torch .view(2,n) reinterpret
__device__ const float c_ox[3][9] = {
    {-1.f, 0.f, 1.f, -1.f, 0.f, 1.f, -1.f, 0.f, 1.f},
    {-1.f, 2.4375f, -1.f, -2.4375f, 1.f, 2.4375f, 1.f, -2.4375f, 0.f},
    {-1.625f, -1.625f, -1.625f, 0.f, -1.625f, 1.625f, 0.f, -1.625f, 0.f}};
__device__ const float c_oy[3][9] = {
    {-1.f, -1.f, -1.f, 0.f, 0.f, 0.f, 1.f, 1.f, 1.f},
    {2.4375f, -1.f, -2.4375f, -1.f, 2.4375f, 1.f, -2.4375f, 1.f, 0.f},
    {0.f, 0.f, 1.625f, 1.625f, -1.625f, 1.625f, 0.f, 1.625f, 1.625f}};

// corner-branch tap tables (16 taps)
__device__ const int tapX_cor[16] = {-1,-1, 2, 3,-1,-1,-3,-2, 1, 1, 2, 3, 1, 1,-3,-2};
__device__ const int tapY_cor[16] = { 2, 3,-1,-1,-3,-2,-1,-1, 2, 3, 1, 1,-3,-2, 1, 1};
__device__ const int tapR_cor[16] = { 4, 5, 2, 2, 0, 1, 2, 2, 4, 5, 3, 3, 0, 1, 3, 3};

__device__ inline float cornw(float off, int X) {
    float f = floorf(off);
    float d = off - f;
    int fi = (int)f;
    return (X == fi) ? (1.f - d) : (X == fi + 1) ? d : 0.f;
}

// --------------------------- prep: fold BN + transpose ----------------------
__global__ __launch_bounds__(256) void prep_kernel(P53 ptrs, float* __restrict__ ws) {
    int i = blockIdx.x * 256 + threadIdx.x;
    const float* const* p = ptrs.p;
    if (i < 442368) {  // bf16 wA[tap][g32][M192][j8], ic = g*8+j
        int tap = i / 49152, r = i % 49152;
        int g = r / 1536, r2 = r % 1536;
        int M = r2 >> 3, j = r2 & 7;
        int br = M >> 6, oc = M & 63, ic = g * 8 + j;
        float v = p[1 + 6 * br][(oc * 256 + ic) * 9 + tap] * p[3 + 6 * br][oc];
        ((ushortT*)(ws + OFF_CWT))[i] = f2bf(v);
        return;
    }
    i -= 442368;
    if (i < 192) {
        int br = i >> 6, oc = i & 63;
        ws[OFF_CB + i] = p[2 + 6 * br][oc] * p[3 + 6 * br][oc] + p[4 + 6 * br][oc];
        return;
    }
    i -= 192;
    if (i < 27648) {  // bf16 wH[br][u72][m16][j8]: u = t*8+g, ic = g*8+j
        int j = i & 7, m = (i >> 3) & 15, u = (i >> 7) % 72, br = i / 9216;
        int cnt = (br == 1) ? 12 : 3;
        int t = u >> 3, g = u & 7, ic = g * 8 + j;
        const float* hw = (br == 0) ? p[5] : (br == 1) ? p[11] : p[17];
        float v = (m < cnt) ? hw[(m * 64 + ic) * 9 + t] : 0.f;
        ((ushortT*)(ws + OFF_HWT))[i] = f2bf(v);
        return;
    }
    i -= 27648;
    if (i < 16384) {  // bf16 wQ[kk8][sub4][m64][j8]
        int j = i & 7, m = (i >> 3) & 63, sg = i >> 9;
        int k = (sg >> 2) * 32 + (sg & 3) * 8 + j;
        ((ushortT*)(ws + OFF_QWT))[i] = f2bf(p[19][m * 256 + k] * p[21][m]);
        return;
    }
    i -= 16384;
    if (i < 64) { ws[OFF_QB + i] = p[20][i] * p[21][i] + p[22][i]; return; }
    i -= 64;
    if (i < 483328) {  // W_eff bf16: units ctr[0,84) cor0[84,164) cor1[164,244) fg[244,472)
        int j = i & 7, m = (i >> 3) & 127, ug = i >> 10;
        int br, NG, NT, n, C, chb, ul;
        if (ug < 84)       { br = 0; NG = 9; NT = 9;  n = 9; C = 67; chb = 0;  ul = ug; }
        else if (ug < 164) { br = 1; NG = 5; NT = 16; n = 8; C = 76; chb = 0;  ul = ug - 84; }
        else if (ug < 244) { br = 1; NG = 5; NT = 16; n = 8; C = 76; chb = 40; ul = ug - 164; }
        else               { br = 2; NG = 9; NT = 25; n = 9; C = 67; chb = 0;  ul = ug - 244; }
        int t = ul / NG, g = ul % NG;
        int c = chb + g * 8 + j;
        float v = 0.f;
        if (t < NT && c < C) {
            int X, Y;
            if (br == 0)      { X = t % 3 - 1; Y = t / 3 - 1; }
            else if (br == 1) { X = tapX_cor[t]; Y = tapY_cor[t]; }
            else              { X = t % 5 - 2; Y = t / 5 - 2; }
            const float* wsrc = (m < 64) ? p[23 + 8 * br] : p[27 + 8 * br];
            int mo = (m < 64) ? m : m - 64;
            float sc = (m < 64) ? p[25 + 8 * br][mo] : p[29 + 8 * br][mo];
            int Cn = (C + 2) * n;
            float s = 0.f;
            for (int pp = 0; pp < n; ++pp) {
                float ww = cornw(c_ox[br][pp], X) * cornw(c_oy[br][pp], Y);
                if (ww != 0.f) s += ww * wsrc[mo * Cn + c * n + pp];
            }
            v = s * sc;
        }
        ((ushortT*)(ws + OFF_KVW))[i] = f2bf(v);
        return;
    }
    i -= 483328;
    if (i < 1152) {  // geo GA/GB/GC [br][which][128]
        int br = i / 384, rem = i % 384, which = rem >> 7, m = rem & 127;
        int n = (br == 1) ? 8 : 9, C = (br == 1) ? 76 : 67, Cn = (C + 2) * n;
        const float* wsrc = (m < 64) ? p[23 + 8 * br] : p[27 + 8 * br];
        int mo = (m < 64) ? m : m - 64;
        float sc = (m < 64) ? p[25 + 8 * br][mo] : p[29 + 8 * br][mo];
        float bb = (m < 64) ? p[24 + 8 * br][mo] : p[28 + 8 * br][mo];
        float tt = (m < 64) ? p[26 + 8 * br][mo] : p[30 + 8 * br][mo];
        float v = 0.f;
        if (which == 0) {
            for (int pp = 0; pp < n; ++pp) v += wsrc[mo * Cn + C * n + pp];
            v *= sc;
        } else if (which == 1) {
            for (int pp = 0; pp < n; ++pp) v += wsrc[mo * Cn + (C + 1) * n + pp];
            v *= sc;
        } else {
            for (int pp = 0; pp < n; ++pp)
                v += wsrc[mo * Cn + C * n + pp] * c_ox[br][pp]
                   + wsrc[mo * Cn + (C + 1) * n + pp] * c_oy[br][pp];
            v = v * sc * 0.0078125f + bb * sc + tt;
        }
        ws[OFF_GEO + br * 384 + which * 128 + m] = v;
        return;
    }
    i -= 1152;
    if (i < 81920) {  // bf16 wP1[kk10][sub4][M256][j8], K=320 extended
        int j = i & 7, M = (i >> 3) & 255, sg = i >> 11;
        int k = (sg >> 2) * 32 + (sg & 3) * 8 + j;
        int nh = M >> 6, oc = M & 63;
        float sc = p[49][nh * 64 + oc];
        float v;
        if (k < 256) v = p[47][(nh * 64 + oc) * 272 + k] * sc;
        else {
            int k2 = k - 256, nh2 = k2 >> 4, va = k2 & 15;
            v = (nh2 == nh) ? p[47][(nh * 64 + oc) * 272 + 256 + va] * sc : 0.f;
        }
        ((ushortT*)(ws + OFF_P1WT))[i] = f2bf(v);
        return;
    }
    i -= 81920;
    if (i < 256) { ws[OFF_P1B + i] = p[48][i] * p[49][i] + p[50][i]; return; }
}

// -- pass A+B borders: base -> padded bf16 (pad 1); zero b16 3-px apron ------
__global__ __launch_bounds__(256) void pass_ab(const float* __restrict__ base,
                                               ushortT* __restrict__ a16,
                                               ushortT* __restrict__ b16) {
    int idx = blockIdx.x * 256 + threadIdx.x;
    if (idx < 4 * 32 * 130 * 130) {
        int col = idx % 130, t = idx / 130;
        int row = t % 130; t /= 130;
        int icg = t & 31, b = t >> 5;
        int h = row - 1, w = col - 1;
        unsigned wds[4] = {0u, 0u, 0u, 0u};
        if ((unsigned)h < 128u && (unsigned)w < 128u) {
            const float* s = base + (size_t)(b * 256 + icg * 8) * HW + h * WIMG + w;
            #pragma unroll
            for (int jp = 0; jp < 4; ++jp)
                wds[jp] = packbf(s[(size_t)(2 * jp) * HW], s[(size_t)(2 * jp + 1) * HW]);
        }
        unsigned* d = (unsigned*)(a16 + (size_t)idx * 8);
        d[0] = wds[0]; d[1] = wds[1]; d[2] = wds[2]; d[3] = wds[3];
        return;
    }
    idx -= 4 * 32 * 130 * 130;
    if (idx < 4 * 28 * 134 * 134) {
        int col = idx % 134, row = (idx / 134) % 134;
        if (row < 3 || row >= 131 || col < 3 || col >= 131) {
            unsigned* d = (unsigned*)(b16 + (size_t)idx * 8);
            d[0] = 0u; d[1] = 0u; d[2] = 0u; d[3] = 0u;
        }
    }
}

// ---- conv3x3 base(256) -> 192 feats via 16x16x32 bf16 MFMA -> b16 ----------
// 8 half-stages (4 icg), double-buffered LDS, global_load_lds async staging.
__global__ __launch_bounds__(256) void conv_base_mfma(
    const ushortT* __restrict__ a16, const ushortT* __restrict__ wA,
    const float* __restrict__ cb, ushortT* __restrict__ b16)
{
    const int wv = threadIdx.x >> 6, lane = threadIdx.x & 63;
    const int sub = lane >> 4, ln = lane & 15;
    const int xh = blockIdx.x, h = blockIdx.y, b = blockIdx.z;
    const int x0 = xh * 64;
    __shared__ __align__(16) ushortT sbuf[2][792 * 8];  // 2 x 12,672 B

    floatx4 acc[3][4];
    #pragma unroll
    for (int mt = 0; mt < 3; ++mt)
        #pragma unroll
        for (int nt = 0; nt < 4; ++nt)
            #pragma unroll
            for (int r = 0; r < 4; ++r) acc[mt][nt][r] = 0.f;

    const int wbase = threadIdx.x & ~63;
    auto stage = [&](int s, int buf) {
        #pragma unroll
        for (int it = 0; it < 4; ++it) {
            int idx = threadIdx.x + it * 256;
            if (idx < 792) {
                int col = idx % 66, t2 = idx / 66;
                int r = t2 % 3, icg = t2 / 3;  // icg 0..3
                const ushortT* g = a16 +
                    (((size_t)(b * 32 + s * 4 + icg) * 130 + (h + r)) * 130 + (x0 + col)) * 8;
                gload_lds16(g, &sbuf[buf][(size_t)(it * 256 + wbase) * 8]);
            }
        }
    };
    stage(0, 0);
    for (int s = 0; s < 8; ++s) {
        __syncthreads();                       // drains: stage s data landed
        if (s < 7) stage(s + 1, (s + 1) & 1);  // async into other buffer
        const ushortT* sb = sbuf[s & 1];
        #pragma unroll
        for (int tap = 0; tap < 9; ++tap) {
            const int ky = tap / 3, kx = tap % 3;
            short8 Bf[4];
            #pragma unroll
            for (int nt = 0; nt < 4; ++nt) {
                int c = nt * 16 + ln + kx;
                Bf[nt] = *(const short8*)(sb + ((sub * 3 + ky) * 66 + c) * 8);
            }
            const int g = s * 4 + sub;
            short8 Af[3];
            #pragma unroll
            for (int mt = 0; mt < 3; ++mt) {
                int m = wv * 48 + mt * 16 + ln;
                Af[mt] = *(const short8*)(wA + (((size_t)tap * 32 + g) * 192 + m) * 8);
            }
            #pragma unroll
            for (int mt = 0; mt < 3; ++mt)
                #pragma unroll
                for (int nt = 0; nt < 4; ++nt)
                    acc[mt][nt] = __builtin_amdgcn_mfma_f32_16x16x32_bf16(
                        Af[mt], Bf[nt], acc[mt][nt], 0, 0, 0);
        }
    }
    // epilogue: bias+relu; shfl-combine sub-pairs -> full 16B contiguous stores
    #pragma unroll
    for (int mt = 0; mt < 3; ++mt) {
        int ocq = wv * 48 + mt * 16 + sub * 4;
        #pragma unroll
        for (int nt = 0; nt < 4; ++nt) {
            int px = x0 + nt * 16 + ln;
            float v0 = fmaxf(acc[mt][nt][0] + cb[ocq + 0], 0.f);
            float v1 = fmaxf(acc[mt][nt][1] + cb[ocq + 1], 0.f);
            float v2 = fmaxf(acc[mt][nt][2] + cb[ocq + 2], 0.f);
            float v3 = fmaxf(acc[mt][nt][3] + cb[ocq + 3], 0.f);
            unsigned lo = packbf(v0, v1), hi = packbf(v2, v3);
            unsigned plo = (unsigned)__shfl_down((int)lo, 16);
            unsigned phi = (unsigned)__shfl_down((int)hi, 16);
            if (!(sub & 1)) {
                int br = ocq >> 6, oc = ocq & 63;
                int grp = ((br == 0) ? 0 : (br == 1) ? 9 : 19) + (oc >> 3);
                uintx4 w = {lo, hi, plo, phi};
                *(uintx4*)(b16 +
                    (((size_t)(b * 28 + grp) * 134 + (h + 3)) * 134 + (px + 3)) * 8) = w;
            }
        }
    }
}

// ---- head 3x3 convs via MFMA (M=16 padded maps, K=576) -> out + b16 --------
__global__ __launch_bounds__(256) void conv_head_mfma(
    const ushortT* __restrict__ b16c, const ushortT* __restrict__ wH,
    const float* __restrict__ chb, const float* __restrict__ ohb,
    const float* __restrict__ fhb, float* __restrict__ out,
    ushortT* __restrict__ b16)
{
    const int wv = threadIdx.x >> 6, lane = threadIdx.x & 63;
    const int sub = lane >> 4, ln = lane & 15;
    const int h = blockIdx.x;
    const int br = blockIdx.y % 3, b = blockIdx.y / 3;
    const int cnt = (br == 1) ? 12 : 3;
    const int mapb = (br == 0) ? 0 : (br == 1) ? 3 : 15;
    const int grpb = (br == 0) ? 0 : (br == 1) ? 9 : 19;
    const float* bias = (br == 0) ? chb : (br == 1) ? ohb : fhb;
    __shared__ __align__(16) ushortT sbuf[8 * 3 * 130 * 8];
    const int wbase = threadIdx.x & ~63;

    for (int it = 0; it < 13; ++it) {
        int idx = threadIdx.x + it * 256;
        if (idx < 3120) {
            int col = idx % 130, t2 = idx / 130;
            int r = t2 % 3, g = t2 / 3;
            const ushortT* gp = b16c +
                (((size_t)(b * 28 + grpb + g) * 134 + (h + r + 2)) * 134 + (col + 2)) * 8;
            gload_lds16(gp, sbuf + (size_t)(it * 256 + wbase) * 8);
        }
    }
    __syncthreads();

    floatx4 acc[2];
    #pragma unroll
    for (int nt = 0; nt < 2; ++nt)
        #pragma unroll
        for (int r = 0; r < 4; ++r) acc[nt][r] = 0.f;
    #pragma unroll
    for (int k = 0; k < 18; ++k) {
        int u = k * 4 + sub;
        int t = u >> 3, g = u & 7;
        int dxv = t % 3 - 1, ry = t / 3;
        short8 Af = *(const short8*)(wH + ((size_t)(br * 72 + u) * 16 + ln) * 8);
        #pragma unroll
        for (int nt = 0; nt < 2; ++nt) {
            int c = wv * 32 + nt * 16 + ln + dxv + 1;
            short8 Bf = *(const short8*)(sbuf + ((g * 3 + ry) * 130 + c) * 8);
            acc[nt] = __builtin_amdgcn_mfma_f32_16x16x32_bf16(Af, Bf, acc[nt], 0, 0, 0);
        }
    }
    #pragma unroll
    for (int nt = 0; nt < 2; ++nt) {
        int px = wv * 32 + nt * 16 + ln;
        #pragma unroll
        for (int r = 0; r < 4; ++r) {
            int m = sub * 4 + r;
            if (m < cnt) {
                float v = acc[nt][r] + bias[m];
                out[((size_t)b * 26 + mapb + m) * HW + h * WIMG + px] = v;
                int grp = grpb + 8 + (m >> 3), j = m & 7;
                b16[(((size_t)(b * 28 + grp) * 134 + (h + 3)) * 134 + (px + 3)) * 8 + j]
                    = f2bf(v);
            }
        }
    }
}

// ------ merged kv: sparse-tap conv, wave tiling M64xN32, async staging ------
__global__ __launch_bounds__(256) void kv_all(
    const ushortT* __restrict__ b16, const ushortT* __restrict__ kvw,
    const float* __restrict__ geob, ushortT* __restrict__ kvout)
{
    const int lane = threadIdx.x & 63, wv = threadIdx.x >> 6;
    const int sub = lane >> 4, ln = lane & 15;
    const int mw = wv >> 1, nw = wv & 1;
    const int x0 = blockIdx.x * 64, h = blockIdx.y;
    const int brv = blockIdx.z >> 2, b = blockIdx.z & 3;

    const int NGRP = (brv == 1) ? 5 : 9;
    const int NTAP = (brv == 0) ? 9 : (brv == 1) ? 16 : 25;
    const int ROWS = (brv == 0) ? 3 : (brv == 1) ? 6 : 5;
    const int COLS = (brv == 0) ? 66 : (brv == 1) ? 70 : 68;
    const int XMIN = (brv == 0) ? -1 : (brv == 1) ? -3 : -2;
    const int NCHUNK = (brv == 0) ? 21 : (brv == 1) ? 20 : 57;
    const int NPH = (brv == 1) ? 2 : 1;
    const int UBASE = (brv == 0) ? 0 : (brv == 1) ? 9 : 19;
    const ushortT* wU0 = kvw + ((brv == 0) ? 0 : (brv == 1) ? 86016 : 249856);
    const float* geo = geob + brv * 384;

    __shared__ __align__(16) ushortT sbuf[3060 * 8];  // 48,960 B (fg max)
    __shared__ int lut[232];
    const int wbase = threadIdx.x & ~63;

    if (threadIdx.x < 4 * NCHUNK) {
        int u = threadIdx.x;
        unsigned Mng = 0xFFFFFFFFu / (unsigned)NGRP + 1u;
        int t = (int)__umulhi((unsigned)u, Mng);
        int g = u - t * NGRP;
        if (t >= NTAP) t = 0;
        int dxv, ry;
        if (brv == 0)      { dxv = t % 3 - 1; ry = t / 3; }
        else if (brv == 1) { dxv = tapX_cor[t]; ry = tapR_cor[t]; }
        else               { dxv = t % 5 - 2; ry = t / 5; }
        lut[u] = (g * ROWS + ry) * COLS + (dxv - XMIN);
    }

    floatx4 acc[4][2];
    #pragma unroll
    for (int mt = 0; mt < 4; ++mt)
        #pragma unroll
        for (int nt = 0; nt < 2; ++nt)
            #pragma unroll
            for (int r = 0; r < 4; ++r) acc[mt][nt][r] = 0.f;

    const unsigned Mcols = 0xFFFFFFFFu / (unsigned)COLS + 1u;
    const unsigned Mrows = 0xFFFFFFFFu / (unsigned)ROWS + 1u;
    const int NELEM = NGRP * ROWS * COLS;
    const int NITER = (NELEM + 255) >> 8;

    for (int ph = 0; ph < NPH; ++ph) {
        const ushortT* wU = wU0 + (size_t)ph * (NCHUNK * 4 * 1024);
        __syncthreads();
        for (int it = 0; it < NITER; ++it) {
            int idx = threadIdx.x + it * 256;
            if (idx < NELEM) {
                int row = (int)__umulhi((unsigned)idx, Mcols);
                int col = idx - row * COLS;
                int grp = (int)__umulhi((unsigned)row, Mrows);
                int rw = row - grp * ROWS;
                int dy = (ROWS == 6) ? ((rw < 3) ? rw - 3 : rw - 2) : (rw - (ROWS >> 1));
                const ushortT* gp = b16 +
                    (((size_t)(b * 28 + UBASE + ph * NGRP + grp) * 134 + (h + dy + 3)) * 134
                     + (x0 + col + XMIN + 3)) * 8;
                gload_lds16(gp, sbuf + (size_t)(it * 256 + wbase) * 8);
            }
        }
        __syncthreads();

        short8 A0[4], B0[2], A1[4], B1[2];
        auto ldf = [&](int k, short8 A[4], short8 B[2]) {
            int u = k * 4 + sub;
            int bb = lut[u];
            const ushortT* wp = wU + (size_t)u * 1024;
            #pragma unroll
            for (int mt = 0; mt < 4; ++mt)
                A[mt] = *(const short8*)(wp + (mw * 64 + mt * 16 + ln) * 8);
            #pragma unroll
            for (int nt = 0; nt < 2; ++nt)
                B[nt] = *(const short8*)(sbuf + (size_t)(bb + nw * 32 + nt * 16 + ln) * 8);
        };
        auto dom = [&](short8 A[4], short8 B[2]) {
            #pragma unroll
            for (int mt = 0; mt < 4; ++mt)
                #pragma unroll
                for (int nt = 0; nt < 2; ++nt)
                    acc[mt][nt] = __builtin_amdgcn_mfma_f32_16x16x32_bf16(
                        A[mt], B[nt], acc[mt][nt], 0, 0, 0);
        };
        ldf(0, A0, B0);
        for (int k = 0; k < NCHUNK; k += 2) {
            bool h1 = (k + 1 < NCHUNK);
            if (h1) ldf(k + 1, A1, B1);
            dom(A0, B0);
            if (k + 2 < NCHUNK) ldf(k + 2, A0, B0);
            if (h1) dom(A1, B1);
        }
    }

    // epilogue: + GA*fx + GB*fy + GC, relu, bf16 store
    const float fy = (h + 0.5f) * 0.0078125f;
    #pragma unroll
    for (int mt = 0; mt < 4; ++mt)
        #pragma unroll
        for (int nt = 0; nt < 2; ++nt) {
            int px = x0 + nw * 32 + nt * 16 + ln;
            float fx = (px + 0.5f) * 0.0078125f;
            #pragma unroll
            for (int r = 0; r < 4; ++r) {
                int Mi = mw * 64 + mt * 16 + sub * 4 + r;
                float v = acc[mt][nt][r] + geo[Mi] * fx + geo[128 + Mi] * fy + geo[256 + Mi];
                kvout[((size_t)(brv * 4 + b) * 128 + Mi) * HW + h * WIMG + px] =
                    f2bf(fmaxf(v, 0.f));
            }
        }
}

// -------- fused q-GEMM + attention softmax + p1(MFMA,K=320) + p2 ------------
__global__ __launch_bounds__(256) void attn_pred_mfma(
    float* __restrict__ ws, const float* __restrict__ p2w,
    const float* __restrict__ p2b, float* __restrict__ out)
{
    const int wv = threadIdx.x >> 6, lane = threadIdx.x & 63;
    const int sub = lane >> 4, ln = lane & 15;
    const int px0 = blockIdx.x * 64, b = blockIdx.y;
    const ushortT* wP1 = (const ushortT*)(ws + OFF_P1WT);
    const ushortT* wQ  = (const ushortT*)(ws + OFF_QWT);
    const ushortT* a16 = (const ushortT*)(ws + OFF_A16);
    const ushortT* kv = (const ushortT*)(ws + OFF_KV);
    const float* p1b = ws + OFF_P1B;
    const float* qb  = ws + OFF_QB;
    __shared__ __align__(16) ushortT xbuf[40 * 64 * 8];
    __shared__ __align__(16) ushortT qld[64 * 64];

    const int mypx = threadIdx.x & 63, nh = threadIdx.x >> 6;
    const int gpx = px0 + mypx, hh = gpx >> 7, ww = gpx & 127;
    #pragma unroll
    for (int g2 = 0; g2 < 8; ++g2) {
        int g = nh * 8 + g2;
        const ushortT* gp = a16 +
            (((size_t)(b * 32 + g) * 130 + (hh + 1)) * 130 + (ww + 1)) * 8;
        gload_lds16(gp, xbuf + (size_t)g * 64 * 8);
    }
    __syncthreads();

    {
        floatx4 qacc[4];
        #pragma unroll
        for (int nt = 0; nt < 4; ++nt)
            #pragma unroll
            for (int r = 0; r < 4; ++r) qacc[nt][r] = 0.f;
        #pragma unroll
        for (int kk = 0; kk < 8; ++kk) {
            short8 Af = *(const short8*)(wQ + (((kk * 4 + sub) * 64) + wv * 16 + ln) * 8);
            #pragma unroll
            for (int nt = 0; nt < 4; ++nt) {
                short8 Bf = *(const short8*)(xbuf + (((kk * 4 + sub) * 64) + nt * 16 + ln) * 8);
                qacc[nt] = __builtin_amdgcn_mfma_f32_16x16x32_bf16(Af, Bf, qacc[nt], 0, 0, 0);
            }
        }
        #pragma unroll
        for (int nt = 0; nt < 4; ++nt)
            #pragma unroll
            for (int r = 0; r < 4; ++r) {
                int row = wv * 16 + sub * 4 + r;
                qld[row * 64 + nt * 16 + ln] = f2bf(fmaxf(qacc[nt][r] + qb[row], 0.f));
            }
    }
    __syncthreads();

    {
        float l[3];
        #pragma unroll
        for (int br = 0; br < 3; ++br) {
            float s = 0.f;
            #pragma unroll
            for (int ko = 0; ko < 16; ++ko)
                s = fmaf(bf2f(qld[(nh * 16 + ko) * 64 + mypx]),
                         bf2f(kv[(size_t)((br * 4 + b) * 128 + nh * 16 + ko) * HW + gpx]), s);
            l[br] = s;
        }
        float m = fmaxf(l[0], fmaxf(l[1], l[2]));
        float e0 = __expf(l[0] - m), e1 = __expf(l[1] - m), e2 = __expf(l[2] - m);
        float inv = 1.f / (e0 + e1 + e2);
        float aw0 = e0 * inv, aw1 = e1 * inv, aw2 = e2 * inv;
        #pragma unroll
        for (int vap = 0; vap < 8; ++vap) {
            int va0 = vap * 2, va1 = vap * 2 + 1;
            float a0 =
                aw0 * bf2f(kv[(size_t)((0 * 4 + b) * 128 + 64 + nh * 16 + va0) * HW + gpx]) +
                aw1 * bf2f(kv[(size_t)((1 * 4 + b) * 128 + 64 + nh * 16 + va0) * HW + gpx]) +
                aw2 * bf2f(kv[(size_t)((2 * 4 + b) * 128 + 64 + nh * 16 + va0) * HW + gpx]);
            float a1 =
                aw0 * bf2f(kv[(size_t)((0 * 4 + b) * 128 + 64 + nh * 16 + va1) * HW + gpx]) +
                aw1 * bf2f(kv[(size_t)((1 * 4 + b) * 128 + 64 + nh * 16 + va1) * HW + gpx]) +
                aw2 * bf2f(kv[(size_t)((2 * 4 + b) * 128 + 64 + nh * 16 + va1) * HW + gpx]);
            int g = 32 + nh * 2 + (vap >> 2), wo = vap & 3;
            ((unsigned*)xbuf)[(g * 64 + mypx) * 4 + wo] = packbf(a0, a1);
        }
    }
    __syncthreads();

    floatx4 acc[4][4];
    #pragma unroll
    for (int mt = 0; mt < 4; ++mt)
        #pragma unroll
        for (int nt = 0; nt < 4; ++nt)
            #pragma unroll
            for (int r = 0; r < 4; ++r) acc[mt][nt][r] = 0.f;
    #pragma unroll
    for (int kk = 0; kk < 10; ++kk) {
        short8 Bf[4];
        #pragma unroll
        for (int nt = 0; nt < 4; ++nt)
            Bf[nt] = *(const short8*)(xbuf + (((kk * 4 + sub) * 64) + nt * 16 + ln) * 8);
        #pragma unroll
        for (int mt = 0; mt < 4; ++mt) {
            short8 Af = *(const short8*)(wP1 +
                (((size_t)(kk * 4 + sub) * 256) + wv * 64 + mt * 16 + ln) * 8);
            #pragma unroll
            for (int nt = 0; nt < 4; ++nt)
                acc[mt][nt] = __builtin_amdgcn_mfma_f32_16x16x32_bf16(Af, Bf[nt], acc[mt][nt], 0, 0, 0);
        }
    }

    float po0[4] = {0.f, 0.f, 0.f, 0.f}, po1[4] = {0.f, 0.f, 0.f, 0.f};
    #pragma unroll
    for (int mt = 0; mt < 4; ++mt)
        #pragma unroll
        for (int r = 0; r < 4; ++r) {
            int oc = mt * 16 + sub * 4 + r;
            float bias = p1b[wv * 64 + oc];
            float w0 = p2w[(wv * 2 + 0) * 64 + oc];
            float w1 = p2w[(wv * 2 + 1) * 64 + oc];
            #pragma unroll
            for (int nt = 0; nt < 4; ++nt) {
                float hv = fmaxf(acc[mt][nt][r] + bias, 0.f);
                po0[nt] = fmaf(w0, hv, po0[nt]);
                po1[nt] = fmaf(w1, hv, po1[nt]);
            }
        }
    #pragma unroll
    for (int nt = 0; nt < 4; ++nt) {
        po0[nt] += __shfl_xor(po0[nt], 16);
        po0[nt] += __shfl_xor(po0[nt], 32);
        po1[nt] += __shfl_xor(po1[nt], 16);
        po1[nt] += __shfl_xor(po1[nt], 32);
    }
    if (sub == 0) {
        #pragma unroll
        for (int nt = 0; nt < 4; ++nt) {
            int px = px0 + nt * 16 + ln;
            out[((size_t)b * 26 + 18 + wv * 2 + 0) * HW + px] = po0[nt] + p2b[wv * 2 + 0];
            out[((size_t)b * 26 + 18 + wv * 2 + 1) * HW + px] = po1[nt] + p2b[wv * 2 + 1];
        }
    }
}

// ---------------------------------------------------------------------------
extern "C" void kernel_launch(void* const* d_in, const int* in_sizes, int n_in,
                              void* d_out, int out_size, void* d_ws, size_t ws_size,
                              hipStream_t stream) {
    (void)in_sizes; (void)n_in; (void)out_size; (void)ws_size;
    float* ws  = (float*)d_ws;
    float* out = (float*)d_out;
    const float* base = (const float*)d_in[0];
    P53 ptrs;
    for (int i = 0; i < 53; ++i) ptrs.p[i] = (const float*)d_in[i];

    ushortT* a16 = (ushortT*)(ws + OFF_A16);
    ushortT* b16 = (ushortT*)(ws + OFF_B16);
    ushortT* kvb = (ushortT*)(ws + OFF_KV);

    prep_kernel<<<4115, 256, 0, stream>>>(ptrs, ws);
    pass_ab<<<16306, 256, 0, stream>>>(base, a16, b16);
    conv_base_mfma<<<dim3(2, 128, 4), 256, 0, stream>>>(
        a16, (const ushortT*)(ws + OFF_CWT), ws + OFF_CB, b16);
    conv_head_mfma<<<dim3(128, 12), 256, 0, stream>>>(
        b16, (const ushortT*)(ws + OFF_HWT),
        (const float*)d_in[6], (const float*)d_in[12], (const float*)d_in[18],
        out, b16);
    kv_all<<<dim3(2, 128, 12), 256, 0, stream>>>(
        b16, (const ushortT*)(ws + OFF_KVW), ws + OFF_GEO, kvb);
    attn_pred_mfma<<<dim3(256, 4), 256, 0, stream>>>(ws, (const float*)d_in[51],
                                                     (const float*)d_in[52], out);
}

// Round 12
// 430.012 us; speedup vs baseline: 1.4784x; 1.0124x over previous
//
#include <hip/hip_runtime.h>
#include <hip/hip_bf16.h>
#include <math.h>

// ---------------------------------------------------------------------------
// HydraFusionHead: B=4, IN_CH=256, HEAD_CH=64, H=W=128, NH=4, KEY=VAL=16
// conv_base: 16x16x32 bf16 MFMA implicit GEMM, double-buffered async staging.
// conv_head: MFMA sparse-tap conv -> d_out + b16.
// kv: merged sparse-tap conv kernel, M64xN32 waves, prescaled LDS tap-LUT +
//     linear A-pointer; round-9 channel-major epilogue store (the round-10/11
//     px-major transpose caused replay-only divergence and is reverted).
// attn+predict: round-9 fused q-GEMM + softmax + p1 GEMM (K=320) + p2.
// ---------------------------------------------------------------------------

#define HW 16384
#define WIMG 128

typedef unsigned short ushortT;
typedef __attribute__((ext_vector_type(8))) short short8;
typedef __attribute__((ext_vector_type(4))) float floatx4;
typedef __attribute__((ext_vector_type(4))) unsigned uintx4;

// ws layout (float offsets)
constexpr size_t OFF_KV    = 16777216;             // bf16 [3][4][128][HW] channel-major
constexpr size_t OFF_A16   = 29360128;             // bf16 [4][32][130][130][8]
constexpr size_t OFF_B16   = 38012928;             // bf16 [4][28][134][134][8]
constexpr size_t OFF_CWT   = 46057216;             // bf16 wA [9][32][192][8]
constexpr size_t OFF_CB    = OFF_CWT + 442368;     // [3][64] fp32
constexpr size_t OFF_HWT   = OFF_CB + 192;         // bf16 wH [3][72][16][8]
constexpr size_t OFF_QWT   = OFF_HWT + 20736;      // bf16 wQ
constexpr size_t OFF_QB    = OFF_QWT + 16384;      // [64]
constexpr size_t OFF_KVW   = OFF_QB + 64;          // bf16 W_eff [472][128][8]
constexpr size_t OFF_GEO   = OFF_KVW + 241664;     // fp32 [3][3][128]
constexpr size_t OFF_P1WT  = OFF_GEO + 1152;       // bf16 wP1
constexpr size_t OFF_P1B   = OFF_P1WT + 81920;     // [256]

struct P53 { const float* p[53]; };

__device__ inline ushortT f2bf(float f) {
    unsigned u = __float_as_uint(f);
    unsigned r = (u + 0x7FFFu + ((u >> 16) & 1u)) >> 16;
    return (ushortT)r;
}
__device__ inline unsigned packbf(float a, float b) {
    return (unsigned)f2bf(a) | ((unsigned)f2bf(b) << 16);
}
__device__ inline float bf2f(ushortT u) {
    return __uint_as_float((unsigned)u << 16);
}

// async global->LDS 16B: lds dst = wave-uniform base + lane*16
typedef __attribute__((address_space(3))) ushortT lds_us;
typedef __attribute__((address_space(1))) const ushortT glb_us;
__device__ inline void gload_lds16(const ushortT* g, ushortT* ldsbase) {
    __builtin_amdgcn_global_load_lds((glb_us*)g, (lds_us*)ldsbase, 16, 0, 0);
}

// sample-point offsets (pixel units), faithful to torch .view(2,n) reinterpret
__device__ const float c_ox[3][9] = {
    {-1.f, 0.f, 1.f, -1.f, 0.f, 1.f, -1.f, 0.f, 1.f},
    {-1.f, 2.4375f, -1.f, -2.4375f, 1.f, 2.4375f, 1.f, -2.4375f, 0.f},
    {-1.625f, -1.625f, -1.625f, 0.f, -1.625f, 1.625f, 0.f, -1.625f, 0.f}};
__device__ const float c_oy[3][9] = {
    {-1.f, -1.f, -1.f, 0.f, 0.f, 0.f, 1.f, 1.f, 1.f},
    {2.4375f, -1.f, -2.4375f, -1.f, 2.4375f, 1.f, -2.4375f, 1.f, 0.f},
    {0.f, 0.f, 1.625f, 1.625f, -1.625f, 1.625f, 0.f, 1.625f, 1.625f}};

// corner-branch tap tables (16 taps)
__device__ const int tapX_cor[16] = {-1,-1, 2, 3,-1,-1,-3,-2, 1, 1, 2, 3, 1, 1,-3,-2};
__device__ const int tapY_cor[16] = { 2, 3,-1,-1,-3,-2,-1,-1, 2, 3, 1, 1,-3,-2, 1, 1};
__device__ const int tapR_cor[16] = { 4, 5, 2, 2, 0, 1, 2, 2, 4, 5, 3, 3, 0, 1, 3, 3};

__device__ inline float cornw(float off, int X) {
    float f = floorf(off);
    float d = off - f;
    int fi = (int)f;
    return (X == fi) ? (1.f - d) : (X == fi + 1) ? d : 0.f;
}

// ------------- setup: fold BN + transpose weights + pass_a/b borders --------
__global__ __launch_bounds__(256) void setup_kernel(P53 ptrs, float* __restrict__ ws,
                                                    const float* __restrict__ base,
                                                    ushortT* __restrict__ a16,
                                                    ushortT* __restrict__ b16) {
    int i = blockIdx.x * 256 + threadIdx.x;
    const float* const* p = ptrs.p;
    if (i < 1053312) {
        if (i < 442368) {  // bf16 wA[tap][g32][M192][j8], ic = g*8+j
            int tap = i / 49152, r = i % 49152;
            int g = r / 1536, r2 = r % 1536;
            int M = r2 >> 3, j = r2 & 7;
            int br = M >> 6, oc = M & 63, ic = g * 8 + j;
            float v = p[1 + 6 * br][(oc * 256 + ic) * 9 + tap] * p[3 + 6 * br][oc];
            ((ushortT*)(ws + OFF_CWT))[i] = f2bf(v);
            return;
        }
        i -= 442368;
        if (i < 192) {
            int br = i >> 6, oc = i & 63;
            ws[OFF_CB + i] = p[2 + 6 * br][oc] * p[3 + 6 * br][oc] + p[4 + 6 * br][oc];
            return;
        }
        i -= 192;
        if (i < 27648) {  // bf16 wH[br][u72][m16][j8]
            int j = i & 7, m = (i >> 3) & 15, u = (i >> 7) % 72, br = i / 9216;
            int cnt = (br == 1) ? 12 : 3;
            int t = u >> 3, g = u & 7, ic = g * 8 + j;
            const float* hw = (br == 0) ? p[5] : (br == 1) ? p[11] : p[17];
            float v = (m < cnt) ? hw[(m * 64 + ic) * 9 + t] : 0.f;
            ((ushortT*)(ws + OFF_HWT))[i] = f2bf(v);
            return;
        }
        i -= 27648;
        if (i < 16384) {  // bf16 wQ[kk8][sub4][m64][j8]
            int j = i & 7, m = (i >> 3) & 63, sg = i >> 9;
            int k = (sg >> 2) * 32 + (sg & 3) * 8 + j;
            ((ushortT*)(ws + OFF_QWT))[i] = f2bf(p[19][m * 256 + k] * p[21][m]);
            return;
        }
        i -= 16384;
        if (i < 64) { ws[OFF_QB + i] = p[20][i] * p[21][i] + p[22][i]; return; }
        i -= 64;
        if (i < 483328) {  // W_eff bf16
            int j = i & 7, m = (i >> 3) & 127, ug = i >> 10;
            int br, NG, NT, n, C, chb, ul;
            if (ug < 84)       { br = 0; NG = 9; NT = 9;  n = 9; C = 67; chb = 0;  ul = ug; }
            else if (ug < 164) { br = 1; NG = 5; NT = 16; n = 8; C = 76; chb = 0;  ul = ug - 84; }
            else if (ug < 244) { br = 1; NG = 5; NT = 16; n = 8; C = 76; chb = 40; ul = ug - 164; }
            else               { br = 2; NG = 9; NT = 25; n = 9; C = 67; chb = 0;  ul = ug - 244; }
            int t = ul / NG, g = ul % NG;
            int c = chb + g * 8 + j;
            float v = 0.f;
            if (t < NT && c < C) {
                int X, Y;
                if (br == 0)      { X = t % 3 - 1; Y = t / 3 - 1; }
                else if (br == 1) { X = tapX_cor[t]; Y = tapY_cor[t]; }
                else              { X = t % 5 - 2; Y = t / 5 - 2; }
                const float* wsrc = (m < 64) ? p[23 + 8 * br] : p[27 + 8 * br];
                int mo = (m < 64) ? m : m - 64;
                float sc = (m < 64) ? p[25 + 8 * br][mo] : p[29 + 8 * br][mo];
                int Cn = (C + 2) * n;
                float s = 0.f;
                for (int pp = 0; pp < n; ++pp) {
                    float ww = cornw(c_ox[br][pp], X) * cornw(c_oy[br][pp], Y);
                    if (ww != 0.f) s += ww * wsrc[mo * Cn + c * n + pp];
                }
                v = s * sc;
            }
            ((ushortT*)(ws + OFF_KVW))[i] = f2bf(v);
            return;
        }
        i -= 483328;
        if (i < 1152) {  // geo GA/GB/GC [br][which][128]
            int br = i / 384, rem = i % 384, which = rem >> 7, m = rem & 127;
            int n = (br == 1) ? 8 : 9, C = (br == 1) ? 76 : 67, Cn = (C + 2) * n;
            const float* wsrc = (m < 64) ? p[23 + 8 * br] : p[27 + 8 * br];
            int mo = (m < 64) ? m : m - 64;
            float sc = (m < 64) ? p[25 + 8 * br][mo] : p[29 + 8 * br][mo];
            float bb = (m < 64) ? p[24 + 8 * br][mo] : p[28 + 8 * br][mo];
            float tt = (m < 64) ? p[26 + 8 * br][mo] : p[30 + 8 * br][mo];
            float v = 0.f;
            if (which == 0) {
                for (int pp = 0; pp < n; ++pp) v += wsrc[mo * Cn + C * n + pp];
                v *= sc;
            } else if (which == 1) {
                for (int pp = 0; pp < n; ++pp) v += wsrc[mo * Cn + (C + 1) * n + pp];
                v *= sc;
            } else {
                for (int pp = 0; pp < n; ++pp)
                    v += wsrc[mo * Cn + C * n + pp] * c_ox[br][pp]
                       + wsrc[mo * Cn + (C + 1) * n + pp] * c_oy[br][pp];
                v = v * sc * 0.0078125f + bb * sc + tt;
            }
            ws[OFF_GEO + br * 384 + which * 128 + m] = v;
            return;
        }
        i -= 1152;
        if (i < 81920) {  // bf16 wP1[kk10][sub4][M256][j8], K=320 extended
            int j = i & 7, M = (i >> 3) & 255, sg = i >> 11;
            int k = (sg >> 2) * 32 + (sg & 3) * 8 + j;
            int nh = M >> 6, oc = M & 63;
            float sc = p[49][nh * 64 + oc];
            float v;
            if (k < 256) v = p[47][(nh * 64 + oc) * 272 + k] * sc;
            else {
                int k2 = k - 256, nh2 = k2 >> 4, va = k2 & 15;
                v = (nh2 == nh) ? p[47][(nh * 64 + oc) * 272 + 256 + va] * sc : 0.f;
            }
            ((ushortT*)(ws + OFF_P1WT))[i] = f2bf(v);
            return;
        }
        i -= 81920;
        if (i < 256) { ws[OFF_P1B + i] = p[48][i] * p[49][i] + p[50][i]; }
        return;
    }
    int idx = i - 1053312;
    if (idx < 4 * 32 * 130 * 130) {  // pass A: base -> a16 (pad 1)
        int col = idx % 130, t = idx / 130;
        int row = t % 130; t /= 130;
        int icg = t & 31, b = t >> 5;
        int h = row - 1, w = col - 1;
        unsigned wds[4] = {0u, 0u, 0u, 0u};
        if ((unsigned)h < 128u && (unsigned)w < 128u) {
            const float* s = base + (size_t)(b * 256 + icg * 8) * HW + h * WIMG + w;
            #pragma unroll
            for (int jp = 0; jp < 4; ++jp)
                wds[jp] = packbf(s[(size_t)(2 * jp) * HW], s[(size_t)(2 * jp + 1) * HW]);
        }
        unsigned* d = (unsigned*)(a16 + (size_t)idx * 8);
        d[0] = wds[0]; d[1] = wds[1]; d[2] = wds[2]; d[3] = wds[3];
        return;
    }
    idx -= 4 * 32 * 130 * 130;
    if (idx < 4 * 28 * 134 * 134) {  // b16 3-px apron zero
        int col = idx % 134, row = (idx / 134) % 134;
        if (row < 3 || row >= 131 || col < 3 || col >= 131) {
            unsigned* d = (unsigned*)(b16 + (size_t)idx * 8);
            d[0] = 0u; d[1] = 0u; d[2] = 0u; d[3] = 0u;
        }
    }
}

// ---- conv3x3 base(256) -> 192 feats via 16x16x32 bf16 MFMA -> b16 ----------
__global__ __launch_bounds__(256) void conv_base_mfma(
    const ushortT* __restrict__ a16, const ushortT* __restrict__ wA,
    const float* __restrict__ cb, ushortT* __restrict__ b16)
{
    const int wv = threadIdx.x >> 6, lane = threadIdx.x & 63;
    const int sub = lane >> 4, ln = lane & 15;
    const int xh = blockIdx.x, h = blockIdx.y, b = blockIdx.z;
    const int x0 = xh * 64;
    __shared__ __align__(16) ushortT sbuf[2][792 * 8];

    floatx4 acc[3][4];
    #pragma unroll
    for (int mt = 0; mt < 3; ++mt)
        #pragma unroll
        for (int nt = 0; nt < 4; ++nt)
            #pragma unroll
            for (int r = 0; r < 4; ++r) acc[mt][nt][r] = 0.f;

    const int wbase = threadIdx.x & ~63;
    auto stage = [&](int s, int buf) {
        #pragma unroll
        for (int it = 0; it < 4; ++it) {
            int idx = threadIdx.x + it * 256;
            if (idx < 792) {
                int col = idx % 66, t2 = idx / 66;
                int r = t2 % 3, icg = t2 / 3;
                const ushortT* g = a16 +
                    (((size_t)(b * 32 + s * 4 + icg) * 130 + (h + r)) * 130 + (x0 + col)) * 8;
                gload_lds16(g, &sbuf[buf][(size_t)(it * 256 + wbase) * 8]);
            }
        }
    };
    stage(0, 0);
    for (int s = 0; s < 8; ++s) {
        __syncthreads();
        if (s < 7) stage(s + 1, (s + 1) & 1);
        const ushortT* sb = sbuf[s & 1];
        #pragma unroll
        for (int tap = 0; tap < 9; ++tap) {
            const int ky = tap / 3, kx = tap % 3;
            short8 Bf[4];
            #pragma unroll
            for (int nt = 0; nt < 4; ++nt) {
                int c = nt * 16 + ln + kx;
                Bf[nt] = *(const short8*)(sb + ((sub * 3 + ky) * 66 + c) * 8);
            }
            const int g = s * 4 + sub;
            short8 Af[3];
            #pragma unroll
            for (int mt = 0; mt < 3; ++mt) {
                int m = wv * 48 + mt * 16 + ln;
                Af[mt] = *(const short8*)(wA + (((size_t)tap * 32 + g) * 192 + m) * 8);
            }
            #pragma unroll
            for (int mt = 0; mt < 3; ++mt)
                #pragma unroll
                for (int nt = 0; nt < 4; ++nt)
                    acc[mt][nt] = __builtin_amdgcn_mfma_f32_16x16x32_bf16(
                        Af[mt], Bf[nt], acc[mt][nt], 0, 0, 0);
        }
    }
    #pragma unroll
    for (int mt = 0; mt < 3; ++mt) {
        int ocq = wv * 48 + mt * 16 + sub * 4;
        #pragma unroll
        for (int nt = 0; nt < 4; ++nt) {
            int px = x0 + nt * 16 + ln;
            float v0 = fmaxf(acc[mt][nt][0] + cb[ocq + 0], 0.f);
            float v1 = fmaxf(acc[mt][nt][1] + cb[ocq + 1], 0.f);
            float v2 = fmaxf(acc[mt][nt][2] + cb[ocq + 2], 0.f);
            float v3 = fmaxf(acc[mt][nt][3] + cb[ocq + 3], 0.f);
            unsigned lo = packbf(v0, v1), hi = packbf(v2, v3);
            unsigned plo = (unsigned)__shfl_down((int)lo, 16);
            unsigned phi = (unsigned)__shfl_down((int)hi, 16);
            if (!(sub & 1)) {
                int br = ocq >> 6, oc = ocq & 63;
                int grp = ((br == 0) ? 0 : (br == 1) ? 9 : 19) + (oc >> 3);
                uintx4 w = {lo, hi, plo, phi};
                *(uintx4*)(b16 +
                    (((size_t)(b * 28 + grp) * 134 + (h + 3)) * 134 + (px + 3)) * 8) = w;
            }
        }
    }
}

// ---- head 3x3 convs via MFMA (M=16 padded maps, K=576) -> out + b16 --------
__global__ __launch_bounds__(256) void conv_head_mfma(
    const ushortT* __restrict__ b16c, const ushortT* __restrict__ wH,
    const float* __restrict__ chb, const float* __restrict__ ohb,
    const float* __restrict__ fhb, float* __restrict__ out,
    ushortT* __restrict__ b16)
{
    const int wv = threadIdx.x >> 6, lane = threadIdx.x & 63;
    const int sub = lane >> 4, ln = lane & 15;
    const int h = blockIdx.x;
    const int br = blockIdx.y % 3, b = blockIdx.y / 3;
    const int cnt = (br == 1) ? 12 : 3;
    const int mapb = (br == 0) ? 0 : (br == 1) ? 3 : 15;
    const int grpb = (br == 0) ? 0 : (br == 1) ? 9 : 19;
    const float* bias = (br == 0) ? chb : (br == 1) ? ohb : fhb;
    __shared__ __align__(16) ushortT sbuf[8 * 3 * 130 * 8];
    const int wbase = threadIdx.x & ~63;

    for (int it = 0; it < 13; ++it) {
        int idx = threadIdx.x + it * 256;
        if (idx < 3120) {
            int col = idx % 130, t2 = idx / 130;
            int r = t2 % 3, g = t2 / 3;
            const ushortT* gp = b16c +
                (((size_t)(b * 28 + grpb + g) * 134 + (h + r + 2)) * 134 + (col + 2)) * 8;
            gload_lds16(gp, sbuf + (size_t)(it * 256 + wbase) * 8);
        }
    }
    __syncthreads();

    floatx4 acc[2];
    #pragma unroll
    for (int nt = 0; nt < 2; ++nt)
        #pragma unroll
        for (int r = 0; r < 4; ++r) acc[nt][r] = 0.f;
    #pragma unroll
    for (int k = 0; k < 18; ++k) {
        int u = k * 4 + sub;
        int t = u >> 3, g = u & 7;
        int dxv = t % 3 - 1, ry = t / 3;
        short8 Af = *(const short8*)(wH + ((size_t)(br * 72 + u) * 16 + ln) * 8);
        #pragma unroll
        for (int nt = 0; nt < 2; ++nt) {
            int c = wv * 32 + nt * 16 + ln + dxv + 1;
            short8 Bf = *(const short8*)(sbuf + ((g * 3 + ry) * 130 + c) * 8);
            acc[nt] = __builtin_amdgcn_mfma_f32_16x16x32_bf16(Af, Bf, acc[nt], 0, 0, 0);
        }
    }
    #pragma unroll
    for (int nt = 0; nt < 2; ++nt) {
        int px = wv * 32 + nt * 16 + ln;
        #pragma unroll
        for (int r = 0; r < 4; ++r) {
            int m = sub * 4 + r;
            if (m < cnt) {
                float v = acc[nt][r] + bias[m];
                out[((size_t)b * 26 + mapb + m) * HW + h * WIMG + px] = v;
                int grp = grpb + 8 + (m >> 3), j = m & 7;
                b16[(((size_t)(b * 28 + grp) * 134 + (h + 3)) * 134 + (px + 3)) * 8 + j]
                    = f2bf(v);
            }
        }
    }
}

// ------ merged kv: sparse-tap conv, M64xN32, channel-major epilogue ---------
__global__ __launch_bounds__(256) void kv_all(
    const ushortT* __restrict__ b16, const ushortT* __restrict__ kvw,
    const float* __restrict__ geob, ushortT* __restrict__ kvout)
{
    const int lane = threadIdx.x & 63, wv = threadIdx.x >> 6;
    const int sub = lane >> 4, ln = lane & 15;
    const int mw = wv >> 1, nw = wv & 1;
    const int x0 = blockIdx.x * 64, h = blockIdx.y;
    const int brv = blockIdx.z >> 2, b = blockIdx.z & 3;

    const int NGRP = (brv == 1) ? 5 : 9;
    const int NTAP = (brv == 0) ? 9 : (brv == 1) ? 16 : 25;
    const int ROWS = (brv == 0) ? 3 : (brv == 1) ? 6 : 5;
    const int COLS = (brv == 0) ? 66 : (brv == 1) ? 70 : 68;
    const int XMIN = (brv == 0) ? -1 : (brv == 1) ? -3 : -2;
    const int NCHUNK = (brv == 0) ? 21 : (brv == 1) ? 20 : 57;
    const int NPH = (brv == 1) ? 2 : 1;
    const int UBASE = (brv == 0) ? 0 : (brv == 1) ? 9 : 19;
    const ushortT* wU0 = kvw + ((brv == 0) ? 0 : (brv == 1) ? 86016 : 249856);
    const float* geo = geob + brv * 384;

    __shared__ __align__(16) ushortT sbuf[3060 * 8];  // 48,960 B
    __shared__ int lut[232];
    const int wbase = threadIdx.x & ~63;
    const int thrB = (nw * 32 + ln) * 16;  // byte const for B-frag addr

    if (threadIdx.x < 4 * NCHUNK) {
        int u = threadIdx.x;
        unsigned Mng = 0xFFFFFFFFu / (unsigned)NGRP + 1u;
        int t = (int)__umulhi((unsigned)u, Mng);
        int g = u - t * NGRP;
        if (t >= NTAP) t = 0;
        int dxv, ry;
        if (brv == 0)      { dxv = t % 3 - 1; ry = t / 3; }
        else if (brv == 1) { dxv = tapX_cor[t]; ry = tapR_cor[t]; }
        else               { dxv = t % 5 - 2; ry = t / 5; }
        lut[u] = ((g * ROWS + ry) * COLS + (dxv - XMIN)) * 16;  // byte offset
    }

    floatx4 acc[4][2];
    #pragma unroll
    for (int mt = 0; mt < 4; ++mt)
        #pragma unroll
        for (int nt = 0; nt < 2; ++nt)
            #pragma unroll
            for (int r = 0; r < 4; ++r) acc[mt][nt][r] = 0.f;

    const unsigned Mcols = 0xFFFFFFFFu / (unsigned)COLS + 1u;
    const unsigned Mrows = 0xFFFFFFFFu / (unsigned)ROWS + 1u;
    const int NELEM = NGRP * ROWS * COLS;
    const int NITER = (NELEM + 255) >> 8;

    for (int ph = 0; ph < NPH; ++ph) {
        const ushortT* wU = wU0 + (size_t)ph * (NCHUNK * 4 * 1024);
        const ushortT* wp0 = wU + (size_t)sub * 1024 + (mw * 64 + ln) * 8;
        __syncthreads();
        for (int it = 0; it < NITER; ++it) {
            int idx = threadIdx.x + it * 256;
            if (idx < NELEM) {
                int row = (int)__umulhi((unsigned)idx, Mcols);
                int col = idx - row * COLS;
                int grp = (int)__umulhi((unsigned)row, Mrows);
                int rw = row - grp * ROWS;
                int dy = (ROWS == 6) ? ((rw < 3) ? rw - 3 : rw - 2) : (rw - (ROWS >> 1));
                const ushortT* gp = b16 +
                    (((size_t)(b * 28 + UBASE + ph * NGRP + grp) * 134 + (h + dy + 3)) * 134
                     + (x0 + col + XMIN + 3)) * 8;
                gload_lds16(gp, sbuf + (size_t)(it * 256 + wbase) * 8);
            }
        }
        __syncthreads();

        const char* sb8 = (const char*)sbuf;
        short8 A0[4], B0[2], A1[4], B1[2];
        auto ldf = [&](int k, short8 A[4], short8 B[2]) {
            const ushortT* wp = wp0 + (size_t)k * 4096;
            #pragma unroll
            for (int mt = 0; mt < 4; ++mt)
                A[mt] = *(const short8*)(wp + mt * 128);
            int bb = lut[k * 4 + sub] + thrB;
            #pragma unroll
            for (int nt = 0; nt < 2; ++nt)
                B[nt] = *(const short8*)(sb8 + bb + nt * 256);
        };
        auto dom = [&](short8 A[4], short8 B[2]) {
            #pragma unroll
            for (int mt = 0; mt < 4; ++mt)
                #pragma unroll
                for (int nt = 0; nt < 2; ++nt)
                    acc[mt][nt] = __builtin_amdgcn_mfma_f32_16x16x32_bf16(
                        A[mt], B[nt], acc[mt][nt], 0, 0, 0);
        };
        ldf(0, A0, B0);
        for (int k = 0; k < NCHUNK; k += 2) {
            bool h1 = (k + 1 < NCHUNK);
            if (h1) ldf(k + 1, A1, B1);
            dom(A0, B0);
            if (k + 2 < NCHUNK) ldf(k + 2, A0, B0);
            if (h1) dom(A1, B1);
        }
    }

    // epilogue (round-9 style): + GA*fx + GB*fy + GC, relu, channel-major bf16
    const float fy = (h + 0.5f) * 0.0078125f;
    #pragma unroll
    for (int mt = 0; mt < 4; ++mt)
        #pragma unroll
        for (int nt = 0; nt < 2; ++nt) {
            int px = x0 + nw * 32 + nt * 16 + ln;
            float fx = (px + 0.5f) * 0.0078125f;
            #pragma unroll
            for (int r = 0; r < 4; ++r) {
                int Mi = mw * 64 + mt * 16 + sub * 4 + r;
                float v = acc[mt][nt][r] + geo[Mi] * fx + geo[128 + Mi] * fy + geo[256 + Mi];
                kvout[((size_t)(brv * 4 + b) * 128 + Mi) * HW + h * WIMG + px] =
                    f2bf(fmaxf(v, 0.f));
            }
        }
}

// -------- fused q-GEMM + attention softmax + p1(MFMA,K=320) + p2 ------------
__global__ __launch_bounds__(256) void attn_pred_mfma(
    float* __restrict__ ws, const float* __restrict__ p2w,
    const float* __restrict__ p2b, float* __restrict__ out)
{
    const int wv = threadIdx.x >> 6, lane = threadIdx.x & 63;
    const int sub = lane >> 4, ln = lane & 15;
    const int px0 = blockIdx.x * 64, b = blockIdx.y;
    const ushortT* wP1 = (const ushortT*)(ws + OFF_P1WT);
    const ushortT* wQ  = (const ushortT*)(ws + OFF_QWT);
    const ushortT* a16 = (const ushortT*)(ws + OFF_A16);
    const ushortT* kv = (const ushortT*)(ws + OFF_KV);
    const float* p1b = ws + OFF_P1B;
    const float* qb  = ws + OFF_QB;
    __shared__ __align__(16) ushortT xbuf[40 * 64 * 8];
    __shared__ __align__(16) ushortT qld[64 * 64];

    const int mypx = threadIdx.x & 63, nh = threadIdx.x >> 6;
    const int gpx = px0 + mypx, hh = gpx >> 7, ww = gpx & 127;
    #pragma unroll
    for (int g2 = 0; g2 < 8; ++g2) {
        int g = nh * 8 + g2;
        const ushortT* gp = a16 +
            (((size_t)(b * 32 + g) * 130 + (hh + 1)) * 130 + (ww + 1)) * 8;
        gload_lds16(gp, xbuf + (size_t)g * 64 * 8);
    }
    __syncthreads();

    {
        floatx4 qacc[4];
        #pragma unroll
        for (int nt = 0; nt < 4; ++nt)
            #pragma unroll
            for (int r = 0; r < 4; ++r) qacc[nt][r] = 0.f;
        #pragma unroll
        for (int kk = 0; kk < 8; ++kk) {
            short8 Af = *(const short8*)(wQ + (((kk * 4 + sub) * 64) + wv * 16 + ln) * 8);
            #pragma unroll
            for (int nt = 0; nt < 4; ++nt) {
                short8 Bf = *(const short8*)(xbuf + (((kk * 4 + sub) * 64) + nt * 16 + ln) * 8);
                qacc[nt] = __builtin_amdgcn_mfma_f32_16x16x32_bf16(Af, Bf, qacc[nt], 0, 0, 0);
            }
        }
        #pragma unroll
        for (int nt = 0; nt < 4; ++nt)
            #pragma unroll
            for (int r = 0; r < 4; ++r) {
                int row = wv * 16 + sub * 4 + r;
                qld[row * 64 + nt * 16 + ln] = f2bf(fmaxf(qacc[nt][r] + qb[row], 0.f));
            }
    }
    __syncthreads();

    {
        float l[3];
        #pragma unroll
        for (int br = 0; br < 3; ++br) {
            float s = 0.f;
            #pragma unroll
            for (int ko = 0; ko < 16; ++ko)
                s = fmaf(bf2f(qld[(nh * 16 + ko) * 64 + mypx]),
                         bf2f(kv[(size_t)((br * 4 + b) * 128 + nh * 16 + ko) * HW + gpx]), s);
            l[br] = s;
        }
        float m = fmaxf(l[0], fmaxf(l[1], l[2]));
        float e0 = __expf(l[0] - m), e1 = __expf(l[1] - m), e2 = __expf(l[2] - m);
        float inv = 1.f / (e0 + e1 + e2);
        float aw0 = e0 * inv, aw1 = e1 * inv, aw2 = e2 * inv;
        #pragma unroll
        for (int vap = 0; vap < 8; ++vap) {
            int va0 = vap * 2, va1 = vap * 2 + 1;
            float a0 =
                aw0 * bf2f(kv[(size_t)((0 * 4 + b) * 128 + 64 + nh * 16 + va0) * HW + gpx]) +
                aw1 * bf2f(kv[(size_t)((1 * 4 + b) * 128 + 64 + nh * 16 + va0) * HW + gpx]) +
                aw2 * bf2f(kv[(size_t)((2 * 4 + b) * 128 + 64 + nh * 16 + va0) * HW + gpx]);
            float a1 =
                aw0 * bf2f(kv[(size_t)((0 * 4 + b) * 128 + 64 + nh * 16 + va1) * HW + gpx]) +
                aw1 * bf2f(kv[(size_t)((1 * 4 + b) * 128 + 64 + nh * 16 + va1) * HW + gpx]) +
                aw2 * bf2f(kv[(size_t)((2 * 4 + b) * 128 + 64 + nh * 16 + va1) * HW + gpx]);
            int g = 32 + nh * 2 + (vap >> 2), wo = vap & 3;
            ((unsigned*)xbuf)[(g * 64 + mypx) * 4 + wo] = packbf(a0, a1);
        }
    }
    __syncthreads();

    floatx4 acc[4][4];
    #pragma unroll
    for (int mt = 0; mt < 4; ++mt)
        #pragma unroll
        for (int nt = 0; nt < 4; ++nt)
            #pragma unroll
            for (int r = 0; r < 4; ++r) acc[mt][nt][r] = 0.f;
    #pragma unroll
    for (int kk = 0; kk < 10; ++kk) {
        short8 Bf[4];
        #pragma unroll
        for (int nt = 0; nt < 4; ++nt)
            Bf[nt] = *(const short8*)(xbuf + (((kk * 4 + sub) * 64) + nt * 16 + ln) * 8);
        #pragma unroll
        for (int mt = 0; mt < 4; ++mt) {
            short8 Af = *(const short8*)(wP1 +
                (((size_t)(kk * 4 + sub) * 256) + wv * 64 + mt * 16 + ln) * 8);
            #pragma unroll
            for (int nt = 0; nt < 4; ++nt)
                acc[mt][nt] = __builtin_amdgcn_mfma_f32_16x16x32_bf16(Af, Bf[nt], acc[mt][nt], 0, 0, 0);
        }
    }

    float po0[4] = {0.f, 0.f, 0.f, 0.f}, po1[4] = {0.f, 0.f, 0.f, 0.f};
    #pragma unroll
    for (int mt = 0; mt < 4; ++mt)
        #pragma unroll
        for (int r = 0; r < 4; ++r) {
            int oc = mt * 16 + sub * 4 + r;
            float bias = p1b[wv * 64 + oc];
            float w0 = p2w[(wv * 2 + 0) * 64 + oc];
            float w1 = p2w[(wv * 2 + 1) * 64 + oc];
            #pragma unroll
            for (int nt = 0; nt < 4; ++nt) {
                float hv = fmaxf(acc[mt][nt][r] + bias, 0.f);
                po0[nt] = fmaf(w0, hv, po0[nt]);
                po1[nt] = fmaf(w1, hv, po1[nt]);
            }
        }
    #pragma unroll
    for (int nt = 0; nt < 4; ++nt) {
        po0[nt] += __shfl_xor(po0[nt], 16);
        po0[nt] += __shfl_xor(po0[nt], 32);
        po1[nt] += __shfl_xor(po1[nt], 16);
        po1[nt] += __shfl_xor(po1[nt], 32);
    }
    if (sub == 0) {
        #pragma unroll
        for (int nt = 0; nt < 4; ++nt) {
            int px = px0 + nt * 16 + ln;
            out[((size_t)b * 26 + 18 + wv * 2 + 0) * HW + px] = po0[nt] + p2b[wv * 2 + 0];
            out[((size_t)b * 26 + 18 + wv * 2 + 1) * HW + px] = po1[nt] + p2b[wv * 2 + 1];
        }
    }
}

// ---------------------------------------------------------------------------
extern "C" void kernel_launch(void* const* d_in, const int* in_sizes, int n_in,
                              void* d_out, int out_size, void* d_ws, size_t ws_size,
                              hipStream_t stream) {
    (void)in_sizes; (void)n_in; (void)out_size; (void)ws_size;
    float* ws  = (float*)d_ws;
    float* out = (float*)d_out;
    const float* base = (const float*)d_in[0];
    P53 ptrs;
    for (int i = 0; i < 53; ++i) ptrs.p[i] = (const float*)d_in[i];

    ushortT* a16 = (ushortT*)(ws + OFF_A16);
    ushortT* b16 = (ushortT*)(ws + OFF_B16);
    ushortT* kvb = (ushortT*)(ws + OFF_KV);

    setup_kernel<<<20421, 256, 0, stream>>>(ptrs, ws, base, a16, b16);
    conv_base_mfma<<<dim3(2, 128, 4), 256, 0, stream>>>(
        a16, (const ushortT*)(ws + OFF_CWT), ws + OFF_CB, b16);
    conv_head_mfma<<<dim3(128, 12), 256, 0, stream>>>(
        b16, (const ushortT*)(ws + OFF_HWT),
        (const float*)d_in[6], (const float*)d_in[12], (const float*)d_in[18],
        out, b16);
    kv_all<<<dim3(2, 128, 12), 256, 0, stream>>>(
        b16, (const ushortT*)(ws + OFF_KVW), ws + OFF_GEO, kvb);
    attn_pred_mfma<<<dim3(256, 4), 256, 0, stream>>>(ws, (const float*)d_in[51],
                                                     (const float*)d_in[52], out);
}